// Round 2
// baseline (1593.354 us; speedup 1.0000x reference)
//
#include <hip/hip_runtime.h>
#include <hip/hip_bf16.h>

#define N_NODES 100000
#define N_EDGES 1600000
#define IN_C 256
#define HID_C 128
#define OUT_C 40

// ---------- helpers ----------
__device__ __forceinline__ float lrelu(float x) { return x > 0.f ? x : 0.2f * x; }

// order-preserving float<->uint encoding for atomicMax
__device__ __forceinline__ unsigned fenc(float f) {
    unsigned u = __float_as_uint(f);
    return (u & 0x80000000u) ? ~u : (u | 0x80000000u);
}
__device__ __forceinline__ float fdec(unsigned u) {
    unsigned v = (u & 0x80000000u) ? (u & 0x7FFFFFFFu) : ~u;
    return __uint_as_float(v);
}
#define ENC_NEG_INF 0x007FFFFFu   // fenc(-inf)

__device__ __forceinline__ float eluf(float x) { return x > 0.f ? x : expm1f(x); }

// ---------- init: accumulators = bias, segmax = -inf, denom = 0 ----------
__global__ __launch_bounds__(256) void init_kernel(
    float* __restrict__ out1, float* __restrict__ out2,
    unsigned* __restrict__ segmax1, float* __restrict__ denom1,
    unsigned* __restrict__ segmax2, float* __restrict__ denom2,
    const float* __restrict__ b1, const float* __restrict__ b2)
{
    int idx = blockIdx.x * 256 + threadIdx.x;
    if (idx < N_NODES * HID_C) out1[idx] = b1[idx & (HID_C - 1)];
    if (idx < N_NODES * OUT_C) out2[idx] = b2[idx % OUT_C];
    if (idx < N_NODES) {
        segmax1[idx] = ENC_NEG_INF; denom1[idx] = 0.f;
        segmax2[idx] = ENC_NEG_INF; denom2[idx] = 0.f;
    }
}

// ---------- GEMM1: xl1[N][128] = x[N][256] @ W1[128][256]^T ----------
__global__ __launch_bounds__(256) void gemm1_kernel(
    const float* __restrict__ x, const float* __restrict__ W,
    float* __restrict__ xl)
{
    const int BM = 64, BN = 128, BK = 32;
    __shared__ float As[BK][BM];   // transposed A tile
    __shared__ float Bs[BK][BN];   // Bs[k][c] = W[c][k]
    int tid = threadIdx.x;
    int bm = blockIdx.x * BM;
    int tn = tid & 15;             // 16 along N, 8 ch each
    int tm = tid >> 4;             // 16 along M, 4 nodes each
    float acc[4][8];
#pragma unroll
    for (int i = 0; i < 4; ++i)
#pragma unroll
        for (int j = 0; j < 8; ++j) acc[i][j] = 0.f;

    for (int k0 = 0; k0 < IN_C; k0 += BK) {
        // A tile: 64 rows x 32 k
        int ar = tid >> 3, ac4 = tid & 7;
#pragma unroll
        for (int rr = 0; rr < 2; ++rr) {
            int r = ar + rr * 32;
            int node = bm + r;
            float4 v = make_float4(0.f, 0.f, 0.f, 0.f);
            if (node < N_NODES)
                v = *(const float4*)(x + (size_t)node * IN_C + k0 + ac4 * 4);
            As[ac4 * 4 + 0][r] = v.x; As[ac4 * 4 + 1][r] = v.y;
            As[ac4 * 4 + 2][r] = v.z; As[ac4 * 4 + 3][r] = v.w;
        }
        // B tile: 128 c x 32 k
        int c = tid & 127, kh = tid >> 7;
        const float* wp = W + (size_t)c * IN_C + k0 + kh * 16;
#pragma unroll
        for (int q = 0; q < 4; ++q) {
            float4 v = *(const float4*)(wp + q * 4);
            Bs[kh * 16 + q * 4 + 0][c] = v.x; Bs[kh * 16 + q * 4 + 1][c] = v.y;
            Bs[kh * 16 + q * 4 + 2][c] = v.z; Bs[kh * 16 + q * 4 + 3][c] = v.w;
        }
        __syncthreads();
#pragma unroll
        for (int kk = 0; kk < BK; ++kk) {
            float4 a  = *(const float4*)&As[kk][tm * 4];
            float4 b0 = *(const float4*)&Bs[kk][tn * 8];
            float4 b1 = *(const float4*)&Bs[kk][tn * 8 + 4];
            float av[4] = {a.x, a.y, a.z, a.w};
            float bv[8] = {b0.x, b0.y, b0.z, b0.w, b1.x, b1.y, b1.z, b1.w};
#pragma unroll
            for (int i = 0; i < 4; ++i)
#pragma unroll
                for (int j = 0; j < 8; ++j) acc[i][j] += av[i] * bv[j];
        }
        __syncthreads();
    }
#pragma unroll
    for (int i = 0; i < 4; ++i) {
        int node = bm + tm * 4 + i;
        if (node < N_NODES) {
            float4 o0 = make_float4(acc[i][0], acc[i][1], acc[i][2], acc[i][3]);
            float4 o1 = make_float4(acc[i][4], acc[i][5], acc[i][6], acc[i][7]);
            *(float4*)(xl + (size_t)node * HID_C + tn * 8)     = o0;
            *(float4*)(xl + (size_t)node * HID_C + tn * 8 + 4) = o1;
        }
    }
}

// ---------- GEMM2 (fused ELU on input): xl2[N][40] = elu(h)[N][128] @ W2[40][128]^T ----------
__global__ __launch_bounds__(256) void gemm2_kernel(
    const float* __restrict__ h, const float* __restrict__ W,
    float* __restrict__ xl2)
{
    const int BM = 128, BN = 40, BK = 32;
    __shared__ float As[BK][BM];
    __shared__ float Bs[BK][BN];
    int tid = threadIdx.x;
    int bm = blockIdx.x * BM;
    int tn = tid & 7;              // 8 along N, 5 ch each
    int tm = tid >> 3;             // 32 along M, 4 nodes each
    float acc[4][5];
#pragma unroll
    for (int i = 0; i < 4; ++i)
#pragma unroll
        for (int j = 0; j < 5; ++j) acc[i][j] = 0.f;

    for (int k0 = 0; k0 < HID_C; k0 += BK) {
        int ar = tid >> 3, ac4 = tid & 7;
#pragma unroll
        for (int rr = 0; rr < 4; ++rr) {
            int r = ar + rr * 32;
            int node = bm + r;
            float4 v = make_float4(0.f, 0.f, 0.f, 0.f);
            if (node < N_NODES)
                v = *(const float4*)(h + (size_t)node * HID_C + k0 + ac4 * 4);
            v.x = eluf(v.x); v.y = eluf(v.y); v.z = eluf(v.z); v.w = eluf(v.w);
            As[ac4 * 4 + 0][r] = v.x; As[ac4 * 4 + 1][r] = v.y;
            As[ac4 * 4 + 2][r] = v.z; As[ac4 * 4 + 3][r] = v.w;
        }
        // B: 40 x 32 = 1280 floats, 5 per thread
#pragma unroll
        for (int q = 0; q < 5; ++q) {
            int f = tid + q * 256;
            int c = f >> 5, k = f & 31;
            Bs[k][c] = W[(size_t)c * HID_C + k0 + k];
        }
        __syncthreads();
#pragma unroll
        for (int kk = 0; kk < BK; ++kk) {
            float4 a = *(const float4*)&As[kk][tm * 4];
            float av[4] = {a.x, a.y, a.z, a.w};
            float bv[5];
#pragma unroll
            for (int j = 0; j < 5; ++j) bv[j] = Bs[kk][tn * 5 + j];
#pragma unroll
            for (int i = 0; i < 4; ++i)
#pragma unroll
                for (int j = 0; j < 5; ++j) acc[i][j] += av[i] * bv[j];
        }
        __syncthreads();
    }
#pragma unroll
    for (int i = 0; i < 4; ++i) {
        int node = bm + tm * 4 + i;
        if (node < N_NODES) {
#pragma unroll
            for (int j = 0; j < 5; ++j)
                xl2[(size_t)node * OUT_C + tn * 5 + j] = acc[i][j];
        }
    }
}

// ---------- per-node attention scalars ----------
template <int C>
__global__ __launch_bounds__(256) void alphas_kernel(
    const float* __restrict__ xl, const float* __restrict__ attl,
    const float* __restrict__ attr, float* __restrict__ al, float* __restrict__ ar)
{
    int wid = blockIdx.x * 4 + (threadIdx.x >> 6);
    int lane = threadIdx.x & 63;
    if (wid >= N_NODES) return;
    const float* row = xl + (size_t)wid * C;
    float sl = 0.f, sr = 0.f;
    if (lane < C) { float v = row[lane]; sl += v * attl[lane]; sr += v * attr[lane]; }
    if (C > 64 && lane + 64 < C) { float v = row[lane + 64]; sl += v * attl[lane + 64]; sr += v * attr[lane + 64]; }
#pragma unroll
    for (int o = 32; o > 0; o >>= 1) { sl += __shfl_xor(sl, o); sr += __shfl_xor(sr, o); }
    if (lane == 0) { al[wid] = sl; ar[wid] = sr; }
}

// ---------- edge pass A: segment max ----------
__global__ __launch_bounds__(256) void edge_max_kernel(
    const int* __restrict__ src, const int* __restrict__ dst,
    const float* __restrict__ al, const float* __restrict__ ar,
    unsigned* __restrict__ segmax)
{
    int e = blockIdx.x * 256 + threadIdx.x;
    if (e >= N_EDGES) return;
    int s = src[e], d = dst[e];
    float ev = lrelu(al[s] + ar[d]);
    atomicMax(&segmax[d], fenc(ev));
}

// ---------- fixup: decode, empty segments -> 0 ----------
__global__ __launch_bounds__(256) void fixmax_kernel(
    const unsigned* __restrict__ segmax, float* __restrict__ segmaxf)
{
    int n = blockIdx.x * 256 + threadIdx.x;
    if (n >= N_NODES) return;
    float m = fdec(segmax[n]);
    segmaxf[n] = (m == -INFINITY) ? 0.f : m;
}

// ---------- edge pass B: denom ----------
__global__ __launch_bounds__(256) void edge_sum_kernel(
    const int* __restrict__ src, const int* __restrict__ dst,
    const float* __restrict__ al, const float* __restrict__ ar,
    const float* __restrict__ segmaxf, float* __restrict__ denom)
{
    int e = blockIdx.x * 256 + threadIdx.x;
    if (e >= N_EDGES) return;
    int s = src[e], d = dst[e];
    float ev = lrelu(al[s] + ar[d]);
    atomicAdd(&denom[d], expf(ev - segmaxf[d]));
}

// ---------- edge pass C: message scatter (wave per edge) ----------
template <int C>
__global__ __launch_bounds__(256) void edge_scatter_kernel(
    const int* __restrict__ src, const int* __restrict__ dst,
    const float* __restrict__ al, const float* __restrict__ ar,
    const float* __restrict__ segmaxf, const float* __restrict__ denom,
    const float* __restrict__ xl, float* __restrict__ outacc)
{
    int e = blockIdx.x * 4 + (threadIdx.x >> 6);
    if (e >= N_EDGES) return;
    int lane = threadIdx.x & 63;
    int s = src[e], d = dst[e];
    float ev = lrelu(al[s] + ar[d]);
    float alpha = expf(ev - segmaxf[d]) / fmaxf(denom[d], 1e-16f);
    const float* xr = xl + (size_t)s * C;
    float* orow = outacc + (size_t)d * C;
    if (C > 64) {
        atomicAdd(&orow[lane], xr[lane] * alpha);
        atomicAdd(&orow[lane + 64], xr[lane + 64] * alpha);
    } else {
        if (lane < C) atomicAdd(&orow[lane], xr[lane] * alpha);
    }
}

// ---------- final: log_softmax over 40 ----------
__global__ __launch_bounds__(256) void final_kernel(
    const float* __restrict__ out2, float* __restrict__ out)
{
    int wid = blockIdx.x * 4 + (threadIdx.x >> 6);
    int lane = threadIdx.x & 63;
    if (wid >= N_NODES) return;
    float v = (lane < OUT_C) ? out2[(size_t)wid * OUT_C + lane] : -INFINITY;
    float m = v;
#pragma unroll
    for (int o = 32; o > 0; o >>= 1) m = fmaxf(m, __shfl_xor(m, o));
    float ex = (lane < OUT_C) ? expf(v - m) : 0.f;
    float ssum = ex;
#pragma unroll
    for (int o = 32; o > 0; o >>= 1) ssum += __shfl_xor(ssum, o);
    if (lane < OUT_C) out[(size_t)wid * OUT_C + lane] = v - m - logf(ssum);
}

extern "C" void kernel_launch(void* const* d_in, const int* in_sizes, int n_in,
                              void* d_out, int out_size, void* d_ws, size_t ws_size,
                              hipStream_t stream)
{
    const float* x    = (const float*)d_in[0];
    const int*   ei   = (const int*)d_in[1];
    const float* W1   = (const float*)d_in[2];
    const float* atl1 = (const float*)d_in[3];
    const float* atr1 = (const float*)d_in[4];
    const float* b1   = (const float*)d_in[5];
    const float* W2   = (const float*)d_in[6];
    const float* atl2 = (const float*)d_in[7];
    const float* atr2 = (const float*)d_in[8];
    const float* b2   = (const float*)d_in[9];
    float* out = (float*)d_out;
    const int* src = ei;
    const int* dst = ei + N_EDGES;

    // workspace layout (floats): total ~34.6M floats = 138.4 MB
    float* ws = (float*)d_ws;
    float* xl1     = ws;                        // 12.8M
    float* out1    = xl1 + (size_t)N_NODES * HID_C;      // 12.8M
    float* xl2     = out1 + (size_t)N_NODES * HID_C;     // 4M
    float* out2    = xl2 + (size_t)N_NODES * OUT_C;      // 4M
    float* al1     = out2 + (size_t)N_NODES * OUT_C;
    float* ar1     = al1 + N_NODES;
    unsigned* smx1 = (unsigned*)(ar1 + N_NODES);
    float* smf1    = (float*)(smx1 + N_NODES);
    float* den1    = smf1 + N_NODES;
    float* al2     = den1 + N_NODES;
    float* ar2     = al2 + N_NODES;
    unsigned* smx2 = (unsigned*)(ar2 + N_NODES);
    float* smf2    = (float*)(smx2 + N_NODES);
    float* den2    = smf2 + N_NODES;
    (void)ws_size; (void)n_in; (void)in_sizes; (void)out_size;

    // init accumulators
    init_kernel<<<(N_NODES * HID_C + 255) / 256, 256, 0, stream>>>(
        out1, out2, smx1, den1, smx2, den2, b1, b2);

    // ---- layer 1 ----
    gemm1_kernel<<<(N_NODES + 63) / 64, 256, 0, stream>>>(x, W1, xl1);
    alphas_kernel<HID_C><<<(N_NODES + 3) / 4, 256, 0, stream>>>(xl1, atl1, atr1, al1, ar1);
    edge_max_kernel<<<(N_EDGES + 255) / 256, 256, 0, stream>>>(src, dst, al1, ar1, smx1);
    fixmax_kernel<<<(N_NODES + 255) / 256, 256, 0, stream>>>(smx1, smf1);
    edge_sum_kernel<<<(N_EDGES + 255) / 256, 256, 0, stream>>>(src, dst, al1, ar1, smf1, den1);
    edge_scatter_kernel<HID_C><<<(N_EDGES + 3) / 4, 256, 0, stream>>>(
        src, dst, al1, ar1, smf1, den1, xl1, out1);

    // ---- layer 2 (ELU fused into GEMM2 input) ----
    gemm2_kernel<<<(N_NODES + 127) / 128, 256, 0, stream>>>(out1, W2, xl2);
    alphas_kernel<OUT_C><<<(N_NODES + 3) / 4, 256, 0, stream>>>(xl2, atl2, atr2, al2, ar2);
    edge_max_kernel<<<(N_EDGES + 255) / 256, 256, 0, stream>>>(src, dst, al2, ar2, smx2);
    fixmax_kernel<<<(N_NODES + 255) / 256, 256, 0, stream>>>(smx2, smf2);
    edge_sum_kernel<<<(N_EDGES + 255) / 256, 256, 0, stream>>>(src, dst, al2, ar2, smf2, den2);
    edge_scatter_kernel<OUT_C><<<(N_EDGES + 3) / 4, 256, 0, stream>>>(
        src, dst, al2, ar2, smf2, den2, xl2, out2);

    // ---- log_softmax ----
    final_kernel<<<(N_NODES + 3) / 4, 256, 0, stream>>>(out2, out);
}

// Round 4
// 755.513 us; speedup vs baseline: 2.1090x; 2.1090x over previous
//
#include <hip/hip_runtime.h>
#include <hip/hip_bf16.h>

#define N_NODES 100000
#define N_EDGES 1600000
#define IN_C 256
#define HID_C 128
#define OUT_C 40
#define NB1 391   // ceil(N_NODES/256)

// ---------- helpers ----------
__device__ __forceinline__ float lrelu(float x) { return x > 0.f ? x : 0.2f * x; }
__device__ __forceinline__ float eluf(float x) { return x > 0.f ? x : expm1f(x); }

// ---------- zero the degree counters ----------
__global__ __launch_bounds__(256) void zero_cnt_kernel(unsigned* __restrict__ cnt)
{
    int i = blockIdx.x * 256 + threadIdx.x;
    if (i < N_NODES) cnt[i] = 0u;
}

// ---------- histogram of dst ----------
__global__ __launch_bounds__(256) void hist_kernel(const int* __restrict__ dst,
                                                   unsigned* __restrict__ cnt)
{
    int e = blockIdx.x * 256 + threadIdx.x;
    if (e < N_EDGES) atomicAdd(&cnt[dst[e]], 1u);
}

// ---------- scan level 1: per-block exclusive scan + block sums ----------
__global__ __launch_bounds__(256) void scan1_kernel(const unsigned* __restrict__ cnt,
                                                    unsigned* __restrict__ partial,
                                                    unsigned* __restrict__ blocksum)
{
    int gid = blockIdx.x * 256 + threadIdx.x;
    unsigned v = (gid < N_NODES) ? cnt[gid] : 0u;
    unsigned orig = v;
    int lane = threadIdx.x & 63, w = threadIdx.x >> 6;
#pragma unroll
    for (int o = 1; o < 64; o <<= 1) {
        unsigned t = __shfl_up(v, o);
        if (lane >= o) v += t;
    }
    __shared__ unsigned wsum[4];
    if (lane == 63) wsum[w] = v;
    __syncthreads();
    unsigned off = 0;
    for (int i = 0; i < w; ++i) off += wsum[i];
    v += off;
    if (gid < N_NODES) partial[gid] = v - orig;     // exclusive within block
    if (threadIdx.x == 255) blocksum[blockIdx.x] = v; // block total
}

// ---------- scan level 2: exclusive scan of block sums (one block) ----------
__global__ __launch_bounds__(512) void scan2_kernel(unsigned* __restrict__ blocksum)
{
    int tid = threadIdx.x;
    unsigned v = (tid < NB1) ? blocksum[tid] : 0u;
    unsigned orig = v;
    int lane = tid & 63, w = tid >> 6;
#pragma unroll
    for (int o = 1; o < 64; o <<= 1) {
        unsigned t = __shfl_up(v, o);
        if (lane >= o) v += t;
    }
    __shared__ unsigned wsum[8];
    if (lane == 63) wsum[w] = v;
    __syncthreads();
    unsigned off = 0;
    for (int i = 0; i < w; ++i) off += wsum[i];
    v += off;
    if (tid < NB1) blocksum[tid] = v - orig;
}

// ---------- scan level 3: combine -> row_start, cursor ----------
__global__ __launch_bounds__(256) void scan3_kernel(const unsigned* __restrict__ partial,
                                                    const unsigned* __restrict__ blocksum,
                                                    unsigned* __restrict__ row_start,
                                                    unsigned* __restrict__ cursor)
{
    int gid = blockIdx.x * 256 + threadIdx.x;
    if (gid < N_NODES) {
        unsigned r = partial[gid] + blocksum[gid >> 8];
        row_start[gid] = r;
        cursor[gid] = r;
    }
}

// ---------- scatter edges into CSR ----------
__global__ __launch_bounds__(256) void scatter_kernel(const int* __restrict__ src,
                                                      const int* __restrict__ dst,
                                                      unsigned* __restrict__ cursor,
                                                      int* __restrict__ csr_src)
{
    int e = blockIdx.x * 256 + threadIdx.x;
    if (e >= N_EDGES) return;
    int d = dst[e];
    unsigned pos = atomicAdd(&cursor[d], 1u);
    csr_src[pos] = src[e];
}

// ---------- GEMM1: xl1[N][128] = x[N][256] @ W1[128][256]^T ----------
__global__ __launch_bounds__(256) void gemm1_kernel(
    const float* __restrict__ x, const float* __restrict__ W,
    float* __restrict__ xl)
{
    const int BM = 64, BN = 128, BK = 32;
    __shared__ float As[BK][BM];
    __shared__ float Bs[BK][BN];
    int tid = threadIdx.x;
    int bm = blockIdx.x * BM;
    int tn = tid & 15;
    int tm = tid >> 4;
    float acc[4][8];
#pragma unroll
    for (int i = 0; i < 4; ++i)
#pragma unroll
        for (int j = 0; j < 8; ++j) acc[i][j] = 0.f;

    for (int k0 = 0; k0 < IN_C; k0 += BK) {
        int ar = tid >> 3, ac4 = tid & 7;
#pragma unroll
        for (int rr = 0; rr < 2; ++rr) {
            int r = ar + rr * 32;
            int node = bm + r;
            float4 v = make_float4(0.f, 0.f, 0.f, 0.f);
            if (node < N_NODES)
                v = *(const float4*)(x + (size_t)node * IN_C + k0 + ac4 * 4);
            As[ac4 * 4 + 0][r] = v.x; As[ac4 * 4 + 1][r] = v.y;
            As[ac4 * 4 + 2][r] = v.z; As[ac4 * 4 + 3][r] = v.w;
        }
        int c = tid & 127, kh = tid >> 7;
        const float* wp = W + (size_t)c * IN_C + k0 + kh * 16;
#pragma unroll
        for (int q = 0; q < 4; ++q) {
            float4 v = *(const float4*)(wp + q * 4);
            Bs[kh * 16 + q * 4 + 0][c] = v.x; Bs[kh * 16 + q * 4 + 1][c] = v.y;
            Bs[kh * 16 + q * 4 + 2][c] = v.z; Bs[kh * 16 + q * 4 + 3][c] = v.w;
        }
        __syncthreads();
#pragma unroll
        for (int kk = 0; kk < BK; ++kk) {
            float4 a  = *(const float4*)&As[kk][tm * 4];
            float4 b0 = *(const float4*)&Bs[kk][tn * 8];
            float4 b1 = *(const float4*)&Bs[kk][tn * 8 + 4];
            float av[4] = {a.x, a.y, a.z, a.w};
            float bv[8] = {b0.x, b0.y, b0.z, b0.w, b1.x, b1.y, b1.z, b1.w};
#pragma unroll
            for (int i = 0; i < 4; ++i)
#pragma unroll
                for (int j = 0; j < 8; ++j) acc[i][j] += av[i] * bv[j];
        }
        __syncthreads();
    }
#pragma unroll
    for (int i = 0; i < 4; ++i) {
        int node = bm + tm * 4 + i;
        if (node < N_NODES) {
            float4 o0 = make_float4(acc[i][0], acc[i][1], acc[i][2], acc[i][3]);
            float4 o1 = make_float4(acc[i][4], acc[i][5], acc[i][6], acc[i][7]);
            *(float4*)(xl + (size_t)node * HID_C + tn * 8)     = o0;
            *(float4*)(xl + (size_t)node * HID_C + tn * 8 + 4) = o1;
        }
    }
}

// ---------- GEMM2: xl2[N][40] = h[N][128] @ W2[40][128]^T  (h already has ELU applied) ----------
__global__ __launch_bounds__(256) void gemm2_kernel(
    const float* __restrict__ h, const float* __restrict__ W,
    float* __restrict__ xl2)
{
    const int BM = 128, BK = 32;
    __shared__ float As[BK][BM];
    __shared__ float Bs[BK][OUT_C];
    int tid = threadIdx.x;
    int bm = blockIdx.x * BM;
    int tn = tid & 7;
    int tm = tid >> 3;
    float acc[4][5];
#pragma unroll
    for (int i = 0; i < 4; ++i)
#pragma unroll
        for (int j = 0; j < 5; ++j) acc[i][j] = 0.f;

    for (int k0 = 0; k0 < HID_C; k0 += BK) {
        int ar = tid >> 3, ac4 = tid & 7;
#pragma unroll
        for (int rr = 0; rr < 4; ++rr) {
            int r = ar + rr * 32;
            int node = bm + r;
            float4 v = make_float4(0.f, 0.f, 0.f, 0.f);
            if (node < N_NODES)
                v = *(const float4*)(h + (size_t)node * HID_C + k0 + ac4 * 4);
            As[ac4 * 4 + 0][r] = v.x; As[ac4 * 4 + 1][r] = v.y;
            As[ac4 * 4 + 2][r] = v.z; As[ac4 * 4 + 3][r] = v.w;
        }
#pragma unroll
        for (int q = 0; q < 5; ++q) {
            int f = tid + q * 256;
            int c = f >> 5, k = f & 31;
            Bs[k][c] = W[(size_t)c * HID_C + k0 + k];
        }
        __syncthreads();
#pragma unroll
        for (int kk = 0; kk < BK; ++kk) {
            float4 a = *(const float4*)&As[kk][tm * 4];
            float av[4] = {a.x, a.y, a.z, a.w};
            float bv[5];
#pragma unroll
            for (int j = 0; j < 5; ++j) bv[j] = Bs[kk][tn * 5 + j];
#pragma unroll
            for (int i = 0; i < 4; ++i)
#pragma unroll
                for (int j = 0; j < 5; ++j) acc[i][j] += av[i] * bv[j];
        }
        __syncthreads();
    }
#pragma unroll
    for (int i = 0; i < 4; ++i) {
        int node = bm + tm * 4 + i;
        if (node < N_NODES) {
#pragma unroll
            for (int j = 0; j < 5; ++j)
                xl2[(size_t)node * OUT_C + tn * 5 + j] = acc[i][j];
        }
    }
}

// ---------- per-node attention scalars ----------
template <int C>
__global__ __launch_bounds__(256) void alphas_kernel(
    const float* __restrict__ xl, const float* __restrict__ attl,
    const float* __restrict__ attr, float* __restrict__ al, float* __restrict__ ar)
{
    int wid = blockIdx.x * 4 + (threadIdx.x >> 6);
    int lane = threadIdx.x & 63;
    if (wid >= N_NODES) return;
    const float* row = xl + (size_t)wid * C;
    float sl = 0.f, sr = 0.f;
    if (lane < C) { float v = row[lane]; sl += v * attl[lane]; sr += v * attr[lane]; }
    if (C > 64 && lane + 64 < C) { float v = row[lane + 64]; sl += v * attl[lane + 64]; sr += v * attr[lane + 64]; }
#pragma unroll
    for (int o = 32; o > 0; o >>= 1) { sl += __shfl_xor(sl, o); sr += __shfl_xor(sr, o); }
    if (lane == 0) { al[wid] = sl; ar[wid] = sr; }
}

// ---------- fused per-node aggregation ----------
// MODE 0: layer 1 -> out[node][128] = elu(sum + b)      (writes h)
// MODE 1: layer 2 -> out[node][40]  = log_softmax(sum + b)
template <int C, int MODE>
__global__ __launch_bounds__(256) void agg_kernel(
    const int* __restrict__ csr_src,
    const unsigned* __restrict__ row_start, const unsigned* __restrict__ row_end,
    const float* __restrict__ al, const float* __restrict__ ar,
    const float* __restrict__ xl, const float* __restrict__ bias,
    float* __restrict__ outp)
{
    int node = blockIdx.x * 4 + (threadIdx.x >> 6);
    int lane = threadIdx.x & 63;
    if (node >= N_NODES) return;
    unsigned beg = row_start[node], end = row_end[node];
    float ar_d = ar[node];

    float mx = 0.f, inv = 0.f;
    float acc0 = 0.f, acc1 = 0.f;
    if (beg != end) {
        // online softmax stats, lane-parallel over edges
        float m_i = -INFINITY, s_i = 0.f;
        for (unsigned i = beg + lane; i < end; i += 64) {
            float e = lrelu(al[csr_src[i]] + ar_d);
            if (e > m_i) { s_i = s_i * __expf(m_i - e) + 1.f; m_i = e; }
            else         { s_i += __expf(e - m_i); }
        }
        mx = m_i;
#pragma unroll
        for (int o = 32; o > 0; o >>= 1) mx = fmaxf(mx, __shfl_xor(mx, o));
        float s_adj = s_i * __expf(m_i - mx);   // m_i==-inf -> s_i==0 -> 0*0
        float sm = s_adj;
#pragma unroll
        for (int o = 32; o > 0; o >>= 1) sm += __shfl_xor(sm, o);
        inv = 1.f / fmaxf(sm, 1e-16f);

        // weighted gather, channel-parallel lanes, serial (unroll 2) over edges
        unsigned i = beg;
        for (; i + 1 < end; i += 2) {
            int s0 = csr_src[i], s1 = csr_src[i + 1];
            float av0 = al[s0], av1 = al[s1];
            const float* xr0 = xl + (size_t)s0 * C;
            const float* xr1 = xl + (size_t)s1 * C;
            float a0 = __expf(lrelu(av0 + ar_d) - mx) * inv;
            float a1 = __expf(lrelu(av1 + ar_d) - mx) * inv;
            if (C > 64) {
                acc0 += xr0[lane] * a0;       acc1 += xr0[lane + 64] * a0;
                acc0 += xr1[lane] * a1;       acc1 += xr1[lane + 64] * a1;
            } else if (lane < C) {
                acc0 += xr0[lane] * a0;
                acc0 += xr1[lane] * a1;
            }
        }
        if (i < end) {
            int s0 = csr_src[i];
            float a0 = __expf(lrelu(al[s0] + ar_d) - mx) * inv;
            const float* xr0 = xl + (size_t)s0 * C;
            if (C > 64) { acc0 += xr0[lane] * a0; acc1 += xr0[lane + 64] * a0; }
            else if (lane < C) acc0 += xr0[lane] * a0;
        }
    }

    if (MODE == 0) {
        outp[(size_t)node * C + lane]      = eluf(acc0 + bias[lane]);
        outp[(size_t)node * C + lane + 64] = eluf(acc1 + bias[lane + 64]);
    } else {
        float v = (lane < C) ? (acc0 + bias[lane]) : -INFINITY;
        float m = v;
#pragma unroll
        for (int o = 32; o > 0; o >>= 1) m = fmaxf(m, __shfl_xor(m, o));
        float ex = (lane < C) ? __expf(v - m) : 0.f;
        float ssum = ex;
#pragma unroll
        for (int o = 32; o > 0; o >>= 1) ssum += __shfl_xor(ssum, o);
        if (lane < C) outp[(size_t)node * C + lane] = v - m - logf(ssum);
    }
}

extern "C" void kernel_launch(void* const* d_in, const int* in_sizes, int n_in,
                              void* d_out, int out_size, void* d_ws, size_t ws_size,
                              hipStream_t stream)
{
    const float* x    = (const float*)d_in[0];
    const int*   ei   = (const int*)d_in[1];
    const float* W1   = (const float*)d_in[2];
    const float* atl1 = (const float*)d_in[3];
    const float* atr1 = (const float*)d_in[4];
    const float* b1   = (const float*)d_in[5];
    const float* W2   = (const float*)d_in[6];
    const float* atl2 = (const float*)d_in[7];
    const float* atr2 = (const float*)d_in[8];
    const float* b2   = (const float*)d_in[9];
    float* out = (float*)d_out;
    const int* src = ei;
    const int* dst = ei + N_EDGES;
    (void)ws_size; (void)n_in; (void)in_sizes; (void)out_size;

    // workspace layout
    float* ws = (float*)d_ws;
    float* xl1      = ws;                                    // 12.8M f
    float* h        = xl1 + (size_t)N_NODES * HID_C;         // 12.8M f
    float* xl2      = h   + (size_t)N_NODES * HID_C;         // 4.0M f
    float* al1      = xl2 + (size_t)N_NODES * OUT_C;
    float* ar1      = al1 + N_NODES;
    float* al2      = ar1 + N_NODES;
    float* ar2      = al2 + N_NODES;
    unsigned* cnt      = (unsigned*)(ar2 + N_NODES);
    unsigned* partial  = cnt + N_NODES;
    unsigned* blocksum = partial + N_NODES;                  // NB1 (pad 512)
    unsigned* row_start= blocksum + 512;
    unsigned* cursor   = row_start + N_NODES;                // becomes row_end after scatter
    int*      csr_src  = (int*)(cursor + N_NODES);           // 1.6M i

    const int EB = (N_EDGES + 255) / 256;
    const int NB4 = (N_NODES + 3) / 4;

    // ---- CSR build (shared by both layers) ----
    zero_cnt_kernel<<<NB1, 256, 0, stream>>>(cnt);
    hist_kernel<<<EB, 256, 0, stream>>>(dst, cnt);
    scan1_kernel<<<NB1, 256, 0, stream>>>(cnt, partial, blocksum);
    scan2_kernel<<<1, 512, 0, stream>>>(blocksum);
    scan3_kernel<<<NB1, 256, 0, stream>>>(partial, blocksum, row_start, cursor);
    scatter_kernel<<<EB, 256, 0, stream>>>(src, dst, cursor, csr_src);

    // ---- layer 1 ----
    gemm1_kernel<<<(N_NODES + 63) / 64, 256, 0, stream>>>(x, W1, xl1);
    alphas_kernel<HID_C><<<NB4, 256, 0, stream>>>(xl1, atl1, atr1, al1, ar1);
    agg_kernel<HID_C, 0><<<NB4, 256, 0, stream>>>(
        csr_src, row_start, cursor, al1, ar1, xl1, b1, h);

    // ---- layer 2 ----
    gemm2_kernel<<<(N_NODES + 127) / 128, 256, 0, stream>>>(h, W2, xl2);
    alphas_kernel<OUT_C><<<NB4, 256, 0, stream>>>(xl2, atl2, atr2, al2, ar2);
    agg_kernel<OUT_C, 1><<<NB4, 256, 0, stream>>>(
        csr_src, row_start, cursor, al2, ar2, xl2, b2, out);
}

// Round 5
// 599.398 us; speedup vs baseline: 2.6583x; 1.2605x over previous
//
#include <hip/hip_runtime.h>
#include <hip/hip_bf16.h>

#define N_NODES 100000
#define N_EDGES 1600000
#define IN_C 256
#define HID_C 128
#define OUT_C 40
#define NB1 391   // ceil(N_NODES/256)

typedef short bf16x8 __attribute__((ext_vector_type(8)));
typedef float f32x4 __attribute__((ext_vector_type(4)));

// ---------- helpers ----------
__device__ __forceinline__ float lrelu(float x) { return x > 0.f ? x : 0.2f * x; }
__device__ __forceinline__ float eluf(float x) { return x > 0.f ? x : expm1f(x); }
__device__ __forceinline__ unsigned short f2bf(float f) {
    unsigned u = __float_as_uint(f);
    unsigned r = (u + 0x7FFFu + ((u >> 16) & 1u)) >> 16;
    return (unsigned short)r;
}

// ---------- zero the degree counters ----------
__global__ __launch_bounds__(256) void zero_cnt_kernel(unsigned* __restrict__ cnt)
{
    int i = blockIdx.x * 256 + threadIdx.x;
    if (i < N_NODES) cnt[i] = 0u;
}

// ---------- rank pass: the ONLY atomic pass. rank[e] = position of e within its dst ----------
__global__ __launch_bounds__(256) void rank_kernel(const int* __restrict__ dst,
                                                   unsigned* __restrict__ cnt,
                                                   unsigned* __restrict__ rank)
{
    int e4 = (blockIdx.x * 256 + threadIdx.x) * 4;
    if (e4 >= N_EDGES) return;
    int4 d = *(const int4*)(dst + e4);
    uint4 r;
    r.x = atomicAdd(&cnt[d.x], 1u);
    r.y = atomicAdd(&cnt[d.y], 1u);
    r.z = atomicAdd(&cnt[d.z], 1u);
    r.w = atomicAdd(&cnt[d.w], 1u);
    *(uint4*)(rank + e4) = r;
}

// ---------- scan level 1: per-block exclusive scan + block sums ----------
__global__ __launch_bounds__(256) void scan1_kernel(const unsigned* __restrict__ cnt,
                                                    unsigned* __restrict__ partial,
                                                    unsigned* __restrict__ blocksum)
{
    int gid = blockIdx.x * 256 + threadIdx.x;
    unsigned v = (gid < N_NODES) ? cnt[gid] : 0u;
    unsigned orig = v;
    int lane = threadIdx.x & 63, w = threadIdx.x >> 6;
#pragma unroll
    for (int o = 1; o < 64; o <<= 1) {
        unsigned t = __shfl_up(v, o);
        if (lane >= o) v += t;
    }
    __shared__ unsigned wsum[4];
    if (lane == 63) wsum[w] = v;
    __syncthreads();
    unsigned off = 0;
    for (int i = 0; i < w; ++i) off += wsum[i];
    v += off;
    if (gid < N_NODES) partial[gid] = v - orig;
    if (threadIdx.x == 255) blocksum[blockIdx.x] = v;
}

// ---------- scan level 2: exclusive scan of block sums (one block) ----------
__global__ __launch_bounds__(512) void scan2_kernel(unsigned* __restrict__ blocksum)
{
    int tid = threadIdx.x;
    unsigned v = (tid < NB1) ? blocksum[tid] : 0u;
    unsigned orig = v;
    int lane = tid & 63, w = tid >> 6;
#pragma unroll
    for (int o = 1; o < 64; o <<= 1) {
        unsigned t = __shfl_up(v, o);
        if (lane >= o) v += t;
    }
    __shared__ unsigned wsum[8];
    if (lane == 63) wsum[w] = v;
    __syncthreads();
    unsigned off = 0;
    for (int i = 0; i < w; ++i) off += wsum[i];
    v += off;
    if (tid < NB1) blocksum[tid] = v - orig;
}

// ---------- scan level 3: combine -> row_start ----------
__global__ __launch_bounds__(256) void scan3_kernel(const unsigned* __restrict__ partial,
                                                    const unsigned* __restrict__ blocksum,
                                                    unsigned* __restrict__ row_start)
{
    int gid = blockIdx.x * 256 + threadIdx.x;
    if (gid < N_NODES) row_start[gid] = partial[gid] + blocksum[gid >> 8];
}

// ---------- place edges into CSR: NO atomics ----------
__global__ __launch_bounds__(256) void place_kernel(const int* __restrict__ src,
                                                    const int* __restrict__ dst,
                                                    const unsigned* __restrict__ rank,
                                                    const unsigned* __restrict__ row_start,
                                                    int* __restrict__ csr_src)
{
    int e4 = (blockIdx.x * 256 + threadIdx.x) * 4;
    if (e4 >= N_EDGES) return;
    int4 d = *(const int4*)(dst + e4);
    int4 s = *(const int4*)(src + e4);
    uint4 r = *(const uint4*)(rank + e4);
    csr_src[row_start[d.x] + r.x] = s.x;
    csr_src[row_start[d.y] + r.y] = s.y;
    csr_src[row_start[d.z] + r.z] = s.z;
    csr_src[row_start[d.w] + r.w] = s.w;
}

// ---------- weight prep: fp32 [realC][KD] -> bf16 [PC][KD], zero-padded ----------
template <int KD, int PC>
__global__ __launch_bounds__(256) void prep_w_kernel(const float* __restrict__ W,
                                                     unsigned short* __restrict__ Wb,
                                                     int realC)
{
    int idx = blockIdx.x * 256 + threadIdx.x;
    if (idx >= PC * KD) return;
    int ch = idx / KD;
    int k = idx & (KD - 1);
    float v = (ch < realC) ? W[(size_t)ch * KD + k] : 0.f;
    Wb[idx] = f2bf(v);
}

// ---------- MFMA GEMM: out[N_NODES][COLS] = A[N_NODES][KD](fp32->bf16) @ Wb[PC][KD]^T ----------
// block = 64 rows (4 waves x 16 rows), NT col-tiles of 16
template <int KD, int NT, int COLS>
__global__ __launch_bounds__(256) void gemm_mfma_kernel(
    const float* __restrict__ A, const unsigned short* __restrict__ Wb,
    float* __restrict__ out)
{
    int tid = threadIdx.x;
    int wv = tid >> 6, lane = tid & 63;
    int bm = blockIdx.x * 64 + wv * 16;
    int r = lane & 15;          // A-row within 16 / B-col / D-col
    int kg = lane >> 4;         // k-group (8 contiguous k each)

    f32x4 acc[NT];
#pragma unroll
    for (int n = 0; n < NT; ++n) acc[n] = (f32x4){0.f, 0.f, 0.f, 0.f};

    int arow = bm + r; if (arow >= N_NODES) arow = N_NODES - 1;
    const float* ap = A + (size_t)arow * KD + kg * 8;
    const unsigned short* bp = Wb + (size_t)r * KD + kg * 8;

    for (int ks = 0; ks < KD / 32; ++ks) {
        float4 a0 = *(const float4*)(ap);
        float4 a1 = *(const float4*)(ap + 4);
        bf16x8 af;
        af[0] = (short)f2bf(a0.x); af[1] = (short)f2bf(a0.y);
        af[2] = (short)f2bf(a0.z); af[3] = (short)f2bf(a0.w);
        af[4] = (short)f2bf(a1.x); af[5] = (short)f2bf(a1.y);
        af[6] = (short)f2bf(a1.z); af[7] = (short)f2bf(a1.w);
#pragma unroll
        for (int n = 0; n < NT; ++n) {
            bf16x8 bf_ = *(const bf16x8*)(bp + (size_t)n * 16 * KD);
            acc[n] = __builtin_amdgcn_mfma_f32_16x16x32_bf16(af, bf_, acc[n], 0, 0, 0);
        }
        ap += 32; bp += 32;
    }

#pragma unroll
    for (int n = 0; n < NT; ++n) {
        int col = n * 16 + r;
        if (col < COLS) {
#pragma unroll
            for (int rr = 0; rr < 4; ++rr) {
                int node = bm + kg * 4 + rr;
                if (node < N_NODES) out[(size_t)node * COLS + col] = acc[n][rr];
            }
        }
    }
}

// ---------- per-node attention scalars ----------
template <int C>
__global__ __launch_bounds__(256) void alphas_kernel(
    const float* __restrict__ xl, const float* __restrict__ attl,
    const float* __restrict__ attr, float* __restrict__ al, float* __restrict__ ar)
{
    int wid = blockIdx.x * 4 + (threadIdx.x >> 6);
    int lane = threadIdx.x & 63;
    if (wid >= N_NODES) return;
    const float* row = xl + (size_t)wid * C;
    float sl = 0.f, sr = 0.f;
    if (lane < C) { float v = row[lane]; sl += v * attl[lane]; sr += v * attr[lane]; }
    if (C > 64 && lane + 64 < C) { float v = row[lane + 64]; sl += v * attl[lane + 64]; sr += v * attr[lane + 64]; }
#pragma unroll
    for (int o = 32; o > 0; o >>= 1) { sl += __shfl_xor(sl, o); sr += __shfl_xor(sr, o); }
    if (lane == 0) { al[wid] = sl; ar[wid] = sr; }
}

// ---------- fused per-node aggregation ----------
// MODE 0: out[node][128] = elu(sum + b)    MODE 1: out[node][40] = log_softmax(sum + b)
template <int C, int MODE>
__global__ __launch_bounds__(256) void agg_kernel(
    const int* __restrict__ csr_src,
    const unsigned* __restrict__ row_start, const unsigned* __restrict__ deg,
    const float* __restrict__ al, const float* __restrict__ ar,
    const float* __restrict__ xl, const float* __restrict__ bias,
    float* __restrict__ outp)
{
    int node = blockIdx.x * 4 + (threadIdx.x >> 6);
    int lane = threadIdx.x & 63;
    if (node >= N_NODES) return;
    unsigned beg = row_start[node];
    unsigned end = beg + deg[node];
    float ar_d = ar[node];

    // ---- softmax stats (branch-free common case: deg <= 64) ----
    unsigned i0 = beg + lane;
    float e0 = (i0 < end) ? lrelu(al[csr_src[i0]] + ar_d) : -INFINITY;
    float m_l = e0;
    for (unsigned i = i0 + 64; i < end; i += 64)
        m_l = fmaxf(m_l, lrelu(al[csr_src[i]] + ar_d));
    float mx = m_l;
#pragma unroll
    for (int o = 32; o > 0; o >>= 1) mx = fmaxf(mx, __shfl_xor(mx, o));
    float s_l = (i0 < end) ? __expf(e0 - mx) : 0.f;
    for (unsigned i = i0 + 64; i < end; i += 64)
        s_l += __expf(lrelu(al[csr_src[i]] + ar_d) - mx);
    float sm = s_l;
#pragma unroll
    for (int o = 32; o > 0; o >>= 1) sm += __shfl_xor(sm, o);
    float inv = 1.f / fmaxf(sm, 1e-16f);

    // ---- weighted gather (channel-parallel, 4-edge unroll, inv hoisted) ----
    float acc0 = 0.f, acc1 = 0.f;
    unsigned i = beg;
    for (; i + 4 <= end; i += 4) {
        int s0 = csr_src[i], s1 = csr_src[i + 1], s2 = csr_src[i + 2], s3 = csr_src[i + 3];
        float w0 = __expf(lrelu(al[s0] + ar_d) - mx);
        float w1 = __expf(lrelu(al[s1] + ar_d) - mx);
        float w2 = __expf(lrelu(al[s2] + ar_d) - mx);
        float w3 = __expf(lrelu(al[s3] + ar_d) - mx);
        const float* p0 = xl + (size_t)s0 * C;
        const float* p1 = xl + (size_t)s1 * C;
        const float* p2 = xl + (size_t)s2 * C;
        const float* p3 = xl + (size_t)s3 * C;
        if (C > 64) {
            acc0 += p0[lane] * w0;      acc1 += p0[lane + 64] * w0;
            acc0 += p1[lane] * w1;      acc1 += p1[lane + 64] * w1;
            acc0 += p2[lane] * w2;      acc1 += p2[lane + 64] * w2;
            acc0 += p3[lane] * w3;      acc1 += p3[lane + 64] * w3;
        } else if (lane < C) {
            acc0 += p0[lane] * w0 + p1[lane] * w1 + p2[lane] * w2 + p3[lane] * w3;
        }
    }
    for (; i < end; ++i) {
        int s0 = csr_src[i];
        float w0 = __expf(lrelu(al[s0] + ar_d) - mx);
        const float* p0 = xl + (size_t)s0 * C;
        if (C > 64) { acc0 += p0[lane] * w0; acc1 += p0[lane + 64] * w0; }
        else if (lane < C) acc0 += p0[lane] * w0;
    }
    acc0 *= inv; acc1 *= inv;

    if (MODE == 0) {
        outp[(size_t)node * C + lane]      = eluf(acc0 + bias[lane]);
        outp[(size_t)node * C + lane + 64] = eluf(acc1 + bias[lane + 64]);
    } else {
        float v = (lane < C) ? (acc0 + bias[lane]) : -INFINITY;
        float m = v;
#pragma unroll
        for (int o = 32; o > 0; o >>= 1) m = fmaxf(m, __shfl_xor(m, o));
        float ex = (lane < C) ? __expf(v - m) : 0.f;
        float ssum = ex;
#pragma unroll
        for (int o = 32; o > 0; o >>= 1) ssum += __shfl_xor(ssum, o);
        if (lane < C) outp[(size_t)node * C + lane] = v - m - logf(ssum);
    }
}

extern "C" void kernel_launch(void* const* d_in, const int* in_sizes, int n_in,
                              void* d_out, int out_size, void* d_ws, size_t ws_size,
                              hipStream_t stream)
{
    const float* x    = (const float*)d_in[0];
    const int*   ei   = (const int*)d_in[1];
    const float* W1   = (const float*)d_in[2];
    const float* atl1 = (const float*)d_in[3];
    const float* atr1 = (const float*)d_in[4];
    const float* b1   = (const float*)d_in[5];
    const float* W2   = (const float*)d_in[6];
    const float* atl2 = (const float*)d_in[7];
    const float* atr2 = (const float*)d_in[8];
    const float* b2   = (const float*)d_in[9];
    float* out = (float*)d_out;
    const int* src = ei;
    const int* dst = ei + N_EDGES;
    (void)ws_size; (void)n_in; (void)in_sizes; (void)out_size;

    // workspace layout (~128 MB)
    float* ws = (float*)d_ws;
    float* xl1      = ws;                                    // 12.8M f
    float* h        = xl1 + (size_t)N_NODES * HID_C;         // 12.8M f
    float* xl2      = h   + (size_t)N_NODES * HID_C;         // 4.0M f  (aliases rank[] during CSR build)
    float* al1      = xl2 + (size_t)N_NODES * OUT_C;
    float* ar1      = al1 + N_NODES;
    float* al2      = ar1 + N_NODES;
    float* ar2      = al2 + N_NODES;
    unsigned* cnt      = (unsigned*)(ar2 + N_NODES);
    unsigned* partial  = cnt + N_NODES;
    unsigned* blocksum = partial + N_NODES;                  // 512 slots
    unsigned* row_start= blocksum + 512;
    int*      csr_src  = (int*)(row_start + N_NODES);        // 1.6M i
    unsigned short* W1b = (unsigned short*)(csr_src + N_EDGES);   // 128*256
    unsigned short* W2b = W1b + HID_C * IN_C;                     // 48*128
    unsigned* rank = (unsigned*)xl2;   // CSR-build-phase only; xl2 written later

    const int EB4 = (N_EDGES / 4 + 255) / 256;
    const int NB4 = (N_NODES + 3) / 4;

    // ---- CSR build: single atomic pass ----
    zero_cnt_kernel<<<NB1, 256, 0, stream>>>(cnt);
    rank_kernel<<<EB4, 256, 0, stream>>>(dst, cnt, rank);
    scan1_kernel<<<NB1, 256, 0, stream>>>(cnt, partial, blocksum);
    scan2_kernel<<<1, 512, 0, stream>>>(blocksum);
    scan3_kernel<<<NB1, 256, 0, stream>>>(partial, blocksum, row_start);
    place_kernel<<<EB4, 256, 0, stream>>>(src, dst, rank, row_start, csr_src);

    // ---- weight prep (bf16) ----
    prep_w_kernel<IN_C, HID_C><<<(HID_C * IN_C + 255) / 256, 256, 0, stream>>>(W1, W1b, HID_C);
    prep_w_kernel<HID_C, 48><<<(48 * HID_C + 255) / 256, 256, 0, stream>>>(W2, W2b, OUT_C);

    // ---- layer 1 ----
    gemm_mfma_kernel<IN_C, 8, HID_C><<<(N_NODES + 63) / 64, 256, 0, stream>>>(x, W1b, xl1);
    alphas_kernel<HID_C><<<NB4, 256, 0, stream>>>(xl1, atl1, atr1, al1, ar1);
    agg_kernel<HID_C, 0><<<NB4, 256, 0, stream>>>(
        csr_src, row_start, cnt, al1, ar1, xl1, b1, h);

    // ---- layer 2 ----
    gemm_mfma_kernel<HID_C, 3, OUT_C><<<(N_NODES + 63) / 64, 256, 0, stream>>>(h, W2b, xl2);
    alphas_kernel<OUT_C><<<NB4, 256, 0, stream>>>(xl2, atl2, atr2, al2, ar2);
    agg_kernel<OUT_C, 1><<<NB4, 256, 0, stream>>>(
        csr_src, row_start, cnt, al2, ar2, xl2, b2, out);
}

// Round 9
// 576.778 us; speedup vs baseline: 2.7625x; 1.0392x over previous
//
#include <hip/hip_runtime.h>
#include <hip/hip_bf16.h>

#define N_NODES 100000
#define N_EDGES 1600000
#define IN_C 256
#define HID_C 128
#define OUT_C 40
#define NB1 391   // ceil(N_NODES/256)

typedef short bf16x8 __attribute__((ext_vector_type(8)));
typedef float f32x4 __attribute__((ext_vector_type(4)));

// ---------- helpers ----------
__device__ __forceinline__ float lrelu(float x) { return x > 0.f ? x : 0.2f * x; }
__device__ __forceinline__ float eluf(float x) { return x > 0.f ? x : expm1f(x); }
__device__ __forceinline__ unsigned short f2bf(float f) {
    unsigned u = __float_as_uint(f);
    unsigned r = (u + 0x7FFFu + ((u >> 16) & 1u)) >> 16;
    return (unsigned short)r;
}
__device__ __forceinline__ float bf_lo(unsigned u) { return __uint_as_float(u << 16); }
__device__ __forceinline__ float bf_hi(unsigned u) { return __uint_as_float(u & 0xFFFF0000u); }

// ---------- zero the degree counters ----------
__global__ __launch_bounds__(256) void zero_cnt_kernel(unsigned* __restrict__ cnt)
{
    int i = blockIdx.x * 256 + threadIdx.x;
    if (i < N_NODES) cnt[i] = 0u;
}

// ---------- rank pass: the ONLY atomic pass ----------
__global__ __launch_bounds__(256) void rank_kernel(const int* __restrict__ dst,
                                                   unsigned* __restrict__ cnt,
                                                   unsigned* __restrict__ rank)
{
    int e4 = (blockIdx.x * 256 + threadIdx.x) * 4;
    if (e4 >= N_EDGES) return;
    int4 d = *(const int4*)(dst + e4);
    uint4 r;
    r.x = atomicAdd(&cnt[d.x], 1u);
    r.y = atomicAdd(&cnt[d.y], 1u);
    r.z = atomicAdd(&cnt[d.z], 1u);
    r.w = atomicAdd(&cnt[d.w], 1u);
    *(uint4*)(rank + e4) = r;
}

// ---------- scan level 1 ----------
__global__ __launch_bounds__(256) void scan1_kernel(const unsigned* __restrict__ cnt,
                                                    unsigned* __restrict__ partial,
                                                    unsigned* __restrict__ blocksum)
{
    int gid = blockIdx.x * 256 + threadIdx.x;
    unsigned v = (gid < N_NODES) ? cnt[gid] : 0u;
    unsigned orig = v;
    int lane = threadIdx.x & 63, w = threadIdx.x >> 6;
#pragma unroll
    for (int o = 1; o < 64; o <<= 1) {
        unsigned t = __shfl_up(v, o);
        if (lane >= o) v += t;
    }
    __shared__ unsigned wsum[4];
    if (lane == 63) wsum[w] = v;
    __syncthreads();
    unsigned off = 0;
    for (int i = 0; i < w; ++i) off += wsum[i];
    v += off;
    if (gid < N_NODES) partial[gid] = v - orig;
    if (threadIdx.x == 255) blocksum[blockIdx.x] = v;
}

// ---------- scan level 2 (one block) ----------
__global__ __launch_bounds__(512) void scan2_kernel(unsigned* __restrict__ blocksum)
{
    int tid = threadIdx.x;
    unsigned v = (tid < NB1) ? blocksum[tid] : 0u;
    unsigned orig = v;
    int lane = tid & 63, w = tid >> 6;
#pragma unroll
    for (int o = 1; o < 64; o <<= 1) {
        unsigned t = __shfl_up(v, o);
        if (lane >= o) v += t;
    }
    __shared__ unsigned wsum[8];
    if (lane == 63) wsum[w] = v;
    __syncthreads();
    unsigned off = 0;
    for (int i = 0; i < w; ++i) off += wsum[i];
    v += off;
    if (tid < NB1) blocksum[tid] = v - orig;
}

// ---------- scan level 3 ----------
__global__ __launch_bounds__(256) void scan3_kernel(const unsigned* __restrict__ partial,
                                                    const unsigned* __restrict__ blocksum,
                                                    unsigned* __restrict__ row_start)
{
    int gid = blockIdx.x * 256 + threadIdx.x;
    if (gid < N_NODES) row_start[gid] = partial[gid] + blocksum[gid >> 8];
}

// ---------- place edges into CSR: NO atomics ----------
__global__ __launch_bounds__(256) void place_kernel(const int* __restrict__ src,
                                                    const int* __restrict__ dst,
                                                    const unsigned* __restrict__ rank,
                                                    const unsigned* __restrict__ row_start,
                                                    int* __restrict__ csr_src)
{
    int e4 = (blockIdx.x * 256 + threadIdx.x) * 4;
    if (e4 >= N_EDGES) return;
    int4 d = *(const int4*)(dst + e4);
    int4 s = *(const int4*)(src + e4);
    uint4 r = *(const uint4*)(rank + e4);
    csr_src[row_start[d.x] + r.x] = s.x;
    csr_src[row_start[d.y] + r.y] = s.y;
    csr_src[row_start[d.z] + r.z] = s.z;
    csr_src[row_start[d.w] + r.w] = s.w;
}

// ---------- weight prep: fp32 [realC][KD] -> bf16 [PC][KD], zero-padded ----------
template <int KD, int PC>
__global__ __launch_bounds__(256) void prep_w_kernel(const float* __restrict__ W,
                                                     unsigned short* __restrict__ Wb,
                                                     int realC)
{
    int idx = blockIdx.x * 256 + threadIdx.x;
    if (idx >= PC * KD) return;
    int ch = idx / KD;
    int k = idx & (KD - 1);
    float v = (ch < realC) ? W[(size_t)ch * KD + k] : 0.f;
    Wb[idx] = f2bf(v);
}

// ---------- GEMM1 (MFMA): xlb[N][128](bf16) = x[N][256](fp32->bf16) @ W1b[128][256]^T ----------
__global__ __launch_bounds__(256) void gemm1_mfma_kernel(
    const float* __restrict__ A, const unsigned short* __restrict__ Wb,
    unsigned short* __restrict__ outb)
{
    const int KD = IN_C, NT = 8, COLS = HID_C;
    int tid = threadIdx.x;
    int wv = tid >> 6, lane = tid & 63;
    int bm = blockIdx.x * 64 + wv * 16;
    int r = lane & 15;
    int kg = lane >> 4;

    f32x4 acc[NT];
#pragma unroll
    for (int n = 0; n < NT; ++n) acc[n] = (f32x4){0.f, 0.f, 0.f, 0.f};

    int arow = bm + r; if (arow >= N_NODES) arow = N_NODES - 1;
    const float* ap = A + (size_t)arow * KD + kg * 8;
    const unsigned short* bp = Wb + (size_t)r * KD + kg * 8;

    for (int ks = 0; ks < KD / 32; ++ks) {
        float4 a0 = *(const float4*)(ap);
        float4 a1 = *(const float4*)(ap + 4);
        bf16x8 af;
        af[0] = (short)f2bf(a0.x); af[1] = (short)f2bf(a0.y);
        af[2] = (short)f2bf(a0.z); af[3] = (short)f2bf(a0.w);
        af[4] = (short)f2bf(a1.x); af[5] = (short)f2bf(a1.y);
        af[6] = (short)f2bf(a1.z); af[7] = (short)f2bf(a1.w);
#pragma unroll
        for (int n = 0; n < NT; ++n) {
            bf16x8 bf_ = *(const bf16x8*)(bp + (size_t)n * 16 * KD);
            acc[n] = __builtin_amdgcn_mfma_f32_16x16x32_bf16(af, bf_, acc[n], 0, 0, 0);
        }
        ap += 32; bp += 32;
    }

#pragma unroll
    for (int n = 0; n < NT; ++n) {
        int col = n * 16 + r;
#pragma unroll
        for (int rr = 0; rr < 4; ++rr) {
            int node = bm + kg * 4 + rr;
            if (node < N_NODES) outb[(size_t)node * COLS + col] = f2bf(acc[n][rr]);
        }
    }
}

// ---------- GEMM2 (MFMA): xl2b[N][40](bf16) = h[N][128](bf16) @ W2b[48][128]^T ----------
__global__ __launch_bounds__(256) void gemm2_mfma_kernel(
    const unsigned short* __restrict__ Ab, const unsigned short* __restrict__ Wb,
    unsigned short* __restrict__ outb)
{
    const int KD = HID_C, NT = 3, COLS = OUT_C;
    int tid = threadIdx.x;
    int wv = tid >> 6, lane = tid & 63;
    int bm = blockIdx.x * 64 + wv * 16;
    int r = lane & 15;
    int kg = lane >> 4;

    f32x4 acc[NT];
#pragma unroll
    for (int n = 0; n < NT; ++n) acc[n] = (f32x4){0.f, 0.f, 0.f, 0.f};

    int arow = bm + r; if (arow >= N_NODES) arow = N_NODES - 1;
    const unsigned short* ap = Ab + (size_t)arow * KD + kg * 8;
    const unsigned short* bp = Wb + (size_t)r * KD + kg * 8;

    for (int ks = 0; ks < KD / 32; ++ks) {
        bf16x8 af = *(const bf16x8*)(ap);
#pragma unroll
        for (int n = 0; n < NT; ++n) {
            bf16x8 bf_ = *(const bf16x8*)(bp + (size_t)n * 16 * KD);
            acc[n] = __builtin_amdgcn_mfma_f32_16x16x32_bf16(af, bf_, acc[n], 0, 0, 0);
        }
        ap += 32; bp += 32;
    }

#pragma unroll
    for (int n = 0; n < NT; ++n) {
        int col = n * 16 + r;
        if (col < COLS) {
#pragma unroll
            for (int rr = 0; rr < 4; ++rr) {
                int node = bm + kg * 4 + rr;
                if (node < N_NODES) outb[(size_t)node * COLS + col] = f2bf(acc[n][rr]);
            }
        }
    }
}

// ---------- per-node attention scalars (bf16 features) ----------
template <int C>
__global__ __launch_bounds__(256) void alphas_kernel(
    const unsigned short* __restrict__ xlb, const float* __restrict__ attl,
    const float* __restrict__ attr, float* __restrict__ al, float* __restrict__ ar)
{
    int wid = blockIdx.x * 4 + (threadIdx.x >> 6);
    int lane = threadIdx.x & 63;
    if (wid >= N_NODES) return;
    float sl = 0.f, sr = 0.f;
    if (2 * lane < C) {
        unsigned u = *(const unsigned*)(xlb + (size_t)wid * C + 2 * lane);
        float lo = bf_lo(u), hi = bf_hi(u);
        sl += lo * attl[2 * lane] + hi * attl[2 * lane + 1];
        sr += lo * attr[2 * lane] + hi * attr[2 * lane + 1];
    }
#pragma unroll
    for (int o = 32; o > 0; o >>= 1) { sl += __shfl_xor(sl, o); sr += __shfl_xor(sr, o); }
    if (lane == 0) { al[wid] = sl; ar[wid] = sr; }
}

// ---------- fused per-node aggregation (bf16 gather) ----------
// MODE 0: h[node][128](bf16) = elu(sum + b)   MODE 1: out[node][40](f32) = log_softmax(sum + b)
template <int C, int MODE>
__global__ __launch_bounds__(256) void agg_kernel(
    const int* __restrict__ csr_src,
    const unsigned* __restrict__ row_start, const unsigned* __restrict__ deg,
    const float* __restrict__ al, const float* __restrict__ ar,
    const unsigned short* __restrict__ xlb, const float* __restrict__ bias,
    void* __restrict__ outp)
{
    int node = blockIdx.x * 4 + (threadIdx.x >> 6);
    int lane = threadIdx.x & 63;
    if (node >= N_NODES) return;
    unsigned beg = row_start[node];
    unsigned end = beg + deg[node];
    float ar_d = ar[node];

    // ---- softmax stats ----
    unsigned i0 = beg + lane;
    float e0 = (i0 < end) ? lrelu(al[csr_src[i0]] + ar_d) : -INFINITY;
    float m_l = e0;
    for (unsigned i = i0 + 64; i < end; i += 64)
        m_l = fmaxf(m_l, lrelu(al[csr_src[i]] + ar_d));
    float mx = m_l;
#pragma unroll
    for (int o = 32; o > 0; o >>= 1) mx = fmaxf(mx, __shfl_xor(mx, o));
    float s_l = (i0 < end) ? __expf(e0 - mx) : 0.f;
    for (unsigned i = i0 + 64; i < end; i += 64)
        s_l += __expf(lrelu(al[csr_src[i]] + ar_d) - mx);
    float sm = s_l;
#pragma unroll
    for (int o = 32; o > 0; o >>= 1) sm += __shfl_xor(sm, o);
    float inv = 1.f / fmaxf(sm, 1e-16f);

    // ---- weighted gather: lane owns cols {2*lane, 2*lane+1}, one dword per edge ----
    const bool act = (2 * lane < C);
    float acc_lo = 0.f, acc_hi = 0.f;
    unsigned i = beg;
    for (; i + 4 <= end; i += 4) {
        int s0 = csr_src[i], s1 = csr_src[i + 1], s2 = csr_src[i + 2], s3 = csr_src[i + 3];
        float w0 = __expf(lrelu(al[s0] + ar_d) - mx);
        float w1 = __expf(lrelu(al[s1] + ar_d) - mx);
        float w2 = __expf(lrelu(al[s2] + ar_d) - mx);
        float w3 = __expf(lrelu(al[s3] + ar_d) - mx);
        if (act) {
            unsigned u0 = *(const unsigned*)(xlb + (size_t)s0 * C + 2 * lane);
            unsigned u1 = *(const unsigned*)(xlb + (size_t)s1 * C + 2 * lane);
            unsigned u2 = *(const unsigned*)(xlb + (size_t)s2 * C + 2 * lane);
            unsigned u3 = *(const unsigned*)(xlb + (size_t)s3 * C + 2 * lane);
            acc_lo += bf_lo(u0) * w0 + bf_lo(u1) * w1 + bf_lo(u2) * w2 + bf_lo(u3) * w3;
            acc_hi += bf_hi(u0) * w0 + bf_hi(u1) * w1 + bf_hi(u2) * w2 + bf_hi(u3) * w3;
        }
    }
    for (; i < end; ++i) {
        int s0 = csr_src[i];
        float w0 = __expf(lrelu(al[s0] + ar_d) - mx);
        if (act) {
            unsigned u0 = *(const unsigned*)(xlb + (size_t)s0 * C + 2 * lane);
            acc_lo += bf_lo(u0) * w0;
            acc_hi += bf_hi(u0) * w0;
        }
    }
    acc_lo *= inv; acc_hi *= inv;

    if (MODE == 0) {
        float vlo = eluf(acc_lo + bias[2 * lane]);
        float vhi = eluf(acc_hi + bias[2 * lane + 1]);
        unsigned p = ((unsigned)f2bf(vhi) << 16) | (unsigned)f2bf(vlo);
        *(unsigned*)((unsigned short*)outp + (size_t)node * C + 2 * lane) = p;
    } else {
        float vlo = act ? (acc_lo + bias[2 * lane])     : -INFINITY;
        float vhi = act ? (acc_hi + bias[2 * lane + 1]) : -INFINITY;
        float m = fmaxf(vlo, vhi);
#pragma unroll
        for (int o = 32; o > 0; o >>= 1) m = fmaxf(m, __shfl_xor(m, o));
        float ex = act ? (__expf(vlo - m) + __expf(vhi - m)) : 0.f;
        float ssum = ex;
#pragma unroll
        for (int o = 32; o > 0; o >>= 1) ssum += __shfl_xor(ssum, o);
        float lg = logf(ssum);
        if (act) {
            float2 o2 = make_float2(vlo - m - lg, vhi - m - lg);
            *(float2*)((float*)outp + (size_t)node * C + 2 * lane) = o2;
        }
    }
}

extern "C" void kernel_launch(void* const* d_in, const int* in_sizes, int n_in,
                              void* d_out, int out_size, void* d_ws, size_t ws_size,
                              hipStream_t stream)
{
    const float* x    = (const float*)d_in[0];
    const int*   ei   = (const int*)d_in[1];
    const float* W1   = (const float*)d_in[2];
    const float* atl1 = (const float*)d_in[3];
    const float* atr1 = (const float*)d_in[4];
    const float* b1   = (const float*)d_in[5];
    const float* W2   = (const float*)d_in[6];
    const float* atl2 = (const float*)d_in[7];
    const float* atr2 = (const float*)d_in[8];
    const float* b2   = (const float*)d_in[9];
    float* out = (float*)d_out;
    const int* src = ei;
    const int* dst = ei + N_EDGES;
    (void)ws_size; (void)n_in; (void)in_sizes; (void)out_size;

    // workspace layout (~68.5 MB)
    char* wsb = (char*)d_ws;
    unsigned short* xlb  = (unsigned short*)wsb;                       // 25.6 MB
    unsigned short* hb   = xlb + (size_t)N_NODES * HID_C;              // 25.6 MB (aliased by rank[] during CSR build)
    unsigned short* xl2b = hb  + (size_t)N_NODES * HID_C;              // 8 MB
    float* al1 = (float*)(xl2b + (size_t)N_NODES * OUT_C);
    float* ar1 = al1 + N_NODES;
    float* al2 = ar1 + N_NODES;
    float* ar2 = al2 + N_NODES;
    unsigned* cnt       = (unsigned*)(ar2 + N_NODES);
    unsigned* partial   = cnt + N_NODES;
    unsigned* blocksum  = partial + N_NODES;        // 512 slots
    unsigned* row_start = blocksum + 512;
    int*      csr_src   = (int*)(row_start + N_NODES);                 // 6.4 MB
    unsigned short* W1b = (unsigned short*)(csr_src + N_EDGES);        // 64 KB
    unsigned short* W2b = W1b + HID_C * IN_C;                          // 12 KB
    unsigned* rank = (unsigned*)hb;   // CSR-build-phase only; hb written later

    const int EB4 = (N_EDGES / 4 + 255) / 256;
    const int NB4 = (N_NODES + 3) / 4;

    // ---- CSR build: single atomic pass ----
    zero_cnt_kernel<<<NB1, 256, 0, stream>>>(cnt);
    rank_kernel<<<EB4, 256, 0, stream>>>(dst, cnt, rank);
    scan1_kernel<<<NB1, 256, 0, stream>>>(cnt, partial, blocksum);
    scan2_kernel<<<1, 512, 0, stream>>>(blocksum);
    scan3_kernel<<<NB1, 256, 0, stream>>>(partial, blocksum, row_start);
    place_kernel<<<EB4, 256, 0, stream>>>(src, dst, rank, row_start, csr_src);

    // ---- weight prep (bf16) ----
    prep_w_kernel<IN_C, HID_C><<<(HID_C * IN_C + 255) / 256, 256, 0, stream>>>(W1, W1b, HID_C);
    prep_w_kernel<HID_C, 48><<<(48 * HID_C + 255) / 256, 256, 0, stream>>>(W2, W2b, OUT_C);

    // ---- layer 1 ----
    gemm1_mfma_kernel<<<(N_NODES + 63) / 64, 256, 0, stream>>>(x, W1b, xlb);
    alphas_kernel<HID_C><<<NB4, 256, 0, stream>>>(xlb, atl1, atr1, al1, ar1);
    agg_kernel<HID_C, 0><<<NB4, 256, 0, stream>>>(
        csr_src, row_start, cnt, al1, ar1, xlb, b1, hb);

    // ---- layer 2 ----
    gemm2_mfma_kernel<<<(N_NODES + 63) / 64, 256, 0, stream>>>(hb, W2b, xl2b);
    alphas_kernel<OUT_C><<<NB4, 256, 0, stream>>>(xl2b, atl2, atr2, al2, ar2);
    agg_kernel<OUT_C, 1><<<NB4, 256, 0, stream>>>(
        csr_src, row_start, cnt, al2, ar2, xl2b, b2, out);
}

// Round 12
// 531.134 us; speedup vs baseline: 2.9999x; 1.0859x over previous
//
#include <hip/hip_runtime.h>
#include <hip/hip_bf16.h>

#define N_NODES 100000
#define N_EDGES 1600000
#define IN_C 256
#define HID_C 128
#define OUT_C 40
#define NB1 391   // ceil(N_NODES/256)

typedef short bf16x8 __attribute__((ext_vector_type(8)));
typedef float f32x4 __attribute__((ext_vector_type(4)));

// ---------- helpers ----------
__device__ __forceinline__ float lrelu(float x) { return x > 0.f ? x : 0.2f * x; }
__device__ __forceinline__ float eluf(float x) { return x > 0.f ? x : expm1f(x); }
__device__ __forceinline__ unsigned short f2bf(float f) {
    unsigned u = __float_as_uint(f);
    unsigned r = (u + 0x7FFFu + ((u >> 16) & 1u)) >> 16;
    return (unsigned short)r;
}
__device__ __forceinline__ float bf_lo(unsigned u) { return __uint_as_float(u << 16); }
__device__ __forceinline__ float bf_hi(unsigned u) { return __uint_as_float(u & 0xFFFF0000u); }

// ---------- zero the degree counters ----------
__global__ __launch_bounds__(256) void zero_cnt_kernel(unsigned* __restrict__ cnt)
{
    int i = blockIdx.x * 256 + threadIdx.x;
    if (i < N_NODES) cnt[i] = 0u;
}

// ---------- rank pass: the ONLY atomic pass ----------
__global__ __launch_bounds__(256) void rank_kernel(const int* __restrict__ dst,
                                                   unsigned* __restrict__ cnt,
                                                   unsigned* __restrict__ rank)
{
    int e4 = (blockIdx.x * 256 + threadIdx.x) * 4;
    if (e4 >= N_EDGES) return;
    int4 d = *(const int4*)(dst + e4);
    uint4 r;
    r.x = atomicAdd(&cnt[d.x], 1u);
    r.y = atomicAdd(&cnt[d.y], 1u);
    r.z = atomicAdd(&cnt[d.z], 1u);
    r.w = atomicAdd(&cnt[d.w], 1u);
    *(uint4*)(rank + e4) = r;
}

// ---------- scan level 1 ----------
__global__ __launch_bounds__(256) void scan1_kernel(const unsigned* __restrict__ cnt,
                                                    unsigned* __restrict__ partial,
                                                    unsigned* __restrict__ blocksum)
{
    int gid = blockIdx.x * 256 + threadIdx.x;
    unsigned v = (gid < N_NODES) ? cnt[gid] : 0u;
    unsigned orig = v;
    int lane = threadIdx.x & 63, w = threadIdx.x >> 6;
#pragma unroll
    for (int o = 1; o < 64; o <<= 1) {
        unsigned t = __shfl_up(v, o);
        if (lane >= o) v += t;
    }
    __shared__ unsigned wsum[4];
    if (lane == 63) wsum[w] = v;
    __syncthreads();
    unsigned off = 0;
    for (int i = 0; i < w; ++i) off += wsum[i];
    v += off;
    if (gid < N_NODES) partial[gid] = v - orig;
    if (threadIdx.x == 255) blocksum[blockIdx.x] = v;
}

// ---------- scan level 2 (one block) ----------
__global__ __launch_bounds__(512) void scan2_kernel(unsigned* __restrict__ blocksum)
{
    int tid = threadIdx.x;
    unsigned v = (tid < NB1) ? blocksum[tid] : 0u;
    unsigned orig = v;
    int lane = tid & 63, w = tid >> 6;
#pragma unroll
    for (int o = 1; o < 64; o <<= 1) {
        unsigned t = __shfl_up(v, o);
        if (lane >= o) v += t;
    }
    __shared__ unsigned wsum[8];
    if (lane == 63) wsum[w] = v;
    __syncthreads();
    unsigned off = 0;
    for (int i = 0; i < w; ++i) off += wsum[i];
    v += off;
    if (tid < NB1) blocksum[tid] = v - orig;
}

// ---------- scan level 3 ----------
__global__ __launch_bounds__(256) void scan3_kernel(const unsigned* __restrict__ partial,
                                                    const unsigned* __restrict__ blocksum,
                                                    unsigned* __restrict__ row_start)
{
    int gid = blockIdx.x * 256 + threadIdx.x;
    if (gid < N_NODES) row_start[gid] = partial[gid] + blocksum[gid >> 8];
}

// ---------- place edges into CSR: NO atomics ----------
__global__ __launch_bounds__(256) void place_kernel(const int* __restrict__ src,
                                                    const int* __restrict__ dst,
                                                    const unsigned* __restrict__ rank,
                                                    const unsigned* __restrict__ row_start,
                                                    int* __restrict__ csr_src)
{
    int e4 = (blockIdx.x * 256 + threadIdx.x) * 4;
    if (e4 >= N_EDGES) return;
    int4 d = *(const int4*)(dst + e4);
    int4 s = *(const int4*)(src + e4);
    uint4 r = *(const uint4*)(rank + e4);
    csr_src[row_start[d.x] + r.x] = s.x;
    csr_src[row_start[d.y] + r.y] = s.y;
    csr_src[row_start[d.z] + r.z] = s.z;
    csr_src[row_start[d.w] + r.w] = s.w;
}

// ---------- weight prep: fp32 [realC][KD] -> bf16 [PC][KD], zero-padded ----------
template <int KD, int PC>
__global__ __launch_bounds__(256) void prep_w_kernel(const float* __restrict__ W,
                                                     unsigned short* __restrict__ Wb,
                                                     int realC)
{
    int idx = blockIdx.x * 256 + threadIdx.x;
    if (idx >= PC * KD) return;
    int ch = idx / KD;
    int k = idx & (KD - 1);
    float v = (ch < realC) ? W[(size_t)ch * KD + k] : 0.f;
    Wb[idx] = f2bf(v);
}

// ---------- GEMM1 (MFMA): xlb[N][128](bf16) = x[N][256](fp32->bf16) @ W1b[128][256]^T ----------
__global__ __launch_bounds__(256) void gemm1_mfma_kernel(
    const float* __restrict__ A, const unsigned short* __restrict__ Wb,
    unsigned short* __restrict__ outb)
{
    const int KD = IN_C, NT = 8, COLS = HID_C;
    int tid = threadIdx.x;
    int wv = tid >> 6, lane = tid & 63;
    int bm = blockIdx.x * 64 + wv * 16;
    int r = lane & 15;
    int kg = lane >> 4;

    f32x4 acc[NT];
#pragma unroll
    for (int n = 0; n < NT; ++n) acc[n] = (f32x4){0.f, 0.f, 0.f, 0.f};

    int arow = bm + r; if (arow >= N_NODES) arow = N_NODES - 1;
    const float* ap = A + (size_t)arow * KD + kg * 8;
    const unsigned short* bp = Wb + (size_t)r * KD + kg * 8;

    for (int ks = 0; ks < KD / 32; ++ks) {
        float4 a0 = *(const float4*)(ap);
        float4 a1 = *(const float4*)(ap + 4);
        bf16x8 af;
        af[0] = (short)f2bf(a0.x); af[1] = (short)f2bf(a0.y);
        af[2] = (short)f2bf(a0.z); af[3] = (short)f2bf(a0.w);
        af[4] = (short)f2bf(a1.x); af[5] = (short)f2bf(a1.y);
        af[6] = (short)f2bf(a1.z); af[7] = (short)f2bf(a1.w);
#pragma unroll
        for (int n = 0; n < NT; ++n) {
            bf16x8 bf_ = *(const bf16x8*)(bp + (size_t)n * 16 * KD);
            acc[n] = __builtin_amdgcn_mfma_f32_16x16x32_bf16(af, bf_, acc[n], 0, 0, 0);
        }
        ap += 32; bp += 32;
    }

#pragma unroll
    for (int n = 0; n < NT; ++n) {
        int col = n * 16 + r;
#pragma unroll
        for (int rr = 0; rr < 4; ++rr) {
            int node = bm + kg * 4 + rr;
            if (node < N_NODES) outb[(size_t)node * COLS + col] = f2bf(acc[n][rr]);
        }
    }
}

// ---------- GEMM2 (MFMA): xl2b[N][40](bf16) = h[N][128](bf16) @ W2b[48][128]^T ----------
__global__ __launch_bounds__(256) void gemm2_mfma_kernel(
    const unsigned short* __restrict__ Ab, const unsigned short* __restrict__ Wb,
    unsigned short* __restrict__ outb)
{
    const int KD = HID_C, NT = 3, COLS = OUT_C;
    int tid = threadIdx.x;
    int wv = tid >> 6, lane = tid & 63;
    int bm = blockIdx.x * 64 + wv * 16;
    int r = lane & 15;
    int kg = lane >> 4;

    f32x4 acc[NT];
#pragma unroll
    for (int n = 0; n < NT; ++n) acc[n] = (f32x4){0.f, 0.f, 0.f, 0.f};

    int arow = bm + r; if (arow >= N_NODES) arow = N_NODES - 1;
    const unsigned short* ap = Ab + (size_t)arow * KD + kg * 8;
    const unsigned short* bp = Wb + (size_t)r * KD + kg * 8;

    for (int ks = 0; ks < KD / 32; ++ks) {
        bf16x8 af = *(const bf16x8*)(ap);
#pragma unroll
        for (int n = 0; n < NT; ++n) {
            bf16x8 bf_ = *(const bf16x8*)(bp + (size_t)n * 16 * KD);
            acc[n] = __builtin_amdgcn_mfma_f32_16x16x32_bf16(af, bf_, acc[n], 0, 0, 0);
        }
        ap += 32; bp += 32;
    }

#pragma unroll
    for (int n = 0; n < NT; ++n) {
        int col = n * 16 + r;
        if (col < COLS) {
#pragma unroll
            for (int rr = 0; rr < 4; ++rr) {
                int node = bm + kg * 4 + rr;
                if (node < N_NODES) outb[(size_t)node * COLS + col] = f2bf(acc[n][rr]);
            }
        }
    }
}

// ---------- per-node attention scalars (bf16 features) ----------
template <int C>
__global__ __launch_bounds__(256) void alphas_kernel(
    const unsigned short* __restrict__ xlb, const float* __restrict__ attl,
    const float* __restrict__ attr, float* __restrict__ al, float* __restrict__ ar)
{
    int wid = blockIdx.x * 4 + (threadIdx.x >> 6);
    int lane = threadIdx.x & 63;
    if (wid >= N_NODES) return;
    float sl = 0.f, sr = 0.f;
    if (2 * lane < C) {
        unsigned u = *(const unsigned*)(xlb + (size_t)wid * C + 2 * lane);
        float lo = bf_lo(u), hi = bf_hi(u);
        sl += lo * attl[2 * lane] + hi * attl[2 * lane + 1];
        sr += lo * attr[2 * lane] + hi * attr[2 * lane + 1];
    }
#pragma unroll
    for (int o = 32; o > 0; o >>= 1) { sl += __shfl_xor(sl, o); sr += __shfl_xor(sr, o); }
    if (lane == 0) { al[wid] = sl; ar[wid] = sr; }
}

// ---------- fused per-node aggregation (bf16 gather, register-held edge weights) ----------
// MODE 0: h[node][128](bf16) = elu(sum + b)   MODE 1: out[node][40](f32) = log_softmax(sum + b)
template <int C, int MODE>
__global__ __launch_bounds__(256) void agg_kernel(
    const int* __restrict__ csr_src,
    const unsigned* __restrict__ row_start, const unsigned* __restrict__ deg,
    const float* __restrict__ al, const float* __restrict__ ar,
    const unsigned short* __restrict__ xlb, const float* __restrict__ bias,
    void* __restrict__ outp)
{
    int node = blockIdx.x * 4 + (threadIdx.x >> 6);
    int lane = threadIdx.x & 63;
    if (node >= N_NODES) return;
    unsigned beg = row_start[node];
    unsigned dn  = deg[node];
    unsigned end = beg + dn;
    float ar_d = ar[node];

    // ---- stats pass: lane j owns edge beg+j (first 64); keeps s_l and w_l in regs ----
    unsigned i0 = beg + lane;
    int   s_l = (i0 < end) ? csr_src[i0] : 0;
    float e0  = (i0 < end) ? lrelu(al[s_l] + ar_d) : -INFINITY;
    float m_l = e0;
    for (unsigned i = i0 + 64; i < end; i += 64)
        m_l = fmaxf(m_l, lrelu(al[csr_src[i]] + ar_d));
    float mx = m_l;
#pragma unroll
    for (int o = 32; o > 0; o >>= 1) mx = fmaxf(mx, __shfl_xor(mx, o));
    float w_l = (i0 < end) ? __expf(e0 - mx) : 0.f;
    float s_sum = w_l;
    for (unsigned i = i0 + 64; i < end; i += 64)
        s_sum += __expf(lrelu(al[csr_src[i]] + ar_d) - mx);
    float sm = s_sum;
#pragma unroll
    for (int o = 32; o > 0; o >>= 1) sm += __shfl_xor(sm, o);
    float inv = 1.f / fmaxf(sm, 1e-16f);

    // ---- weighted gather: broadcast (s_j, w_j) from registers via shfl ----
    constexpr bool FULL = (C >= 128);          // all 64 lanes own a dword
    const bool act = FULL || (2 * lane < C);
    float acc_lo = 0.f, acc_hi = 0.f;
    int nfast = (int)(dn < 64u ? dn : 64u);    // wave-uniform
    int j = 0;
    for (; j + 4 <= nfast; j += 4) {
        float w0 = __shfl(w_l, j),     w1 = __shfl(w_l, j + 1);
        float w2 = __shfl(w_l, j + 2), w3 = __shfl(w_l, j + 3);
        int   s0 = __shfl(s_l, j),     s1 = __shfl(s_l, j + 1);
        int   s2 = __shfl(s_l, j + 2), s3 = __shfl(s_l, j + 3);
        if (act) {
            unsigned u0 = *(const unsigned*)(xlb + (size_t)s0 * C + 2 * lane);
            unsigned u1 = *(const unsigned*)(xlb + (size_t)s1 * C + 2 * lane);
            unsigned u2 = *(const unsigned*)(xlb + (size_t)s2 * C + 2 * lane);
            unsigned u3 = *(const unsigned*)(xlb + (size_t)s3 * C + 2 * lane);
            acc_lo += bf_lo(u0) * w0 + bf_lo(u1) * w1 + bf_lo(u2) * w2 + bf_lo(u3) * w3;
            acc_hi += bf_hi(u0) * w0 + bf_hi(u1) * w1 + bf_hi(u2) * w2 + bf_hi(u3) * w3;
        }
    }
    for (; j < nfast; ++j) {
        float w0 = __shfl(w_l, j);
        int   s0 = __shfl(s_l, j);
        if (act) {
            unsigned u0 = *(const unsigned*)(xlb + (size_t)s0 * C + 2 * lane);
            acc_lo += bf_lo(u0) * w0;
            acc_hi += bf_hi(u0) * w0;
        }
    }
    // rare tail: deg > 64 -> recompute weights (wave-uniform branch)
    for (unsigned i = beg + 64; i < end; ++i) {
        int s0 = csr_src[i];
        float w0 = __expf(lrelu(al[s0] + ar_d) - mx);
        if (act) {
            unsigned u0 = *(const unsigned*)(xlb + (size_t)s0 * C + 2 * lane);
            acc_lo += bf_lo(u0) * w0;
            acc_hi += bf_hi(u0) * w0;
        }
    }
    acc_lo *= inv; acc_hi *= inv;

    if (MODE == 0) {
        float vlo = eluf(acc_lo + bias[2 * lane]);
        float vhi = eluf(acc_hi + bias[2 * lane + 1]);
        unsigned p = ((unsigned)f2bf(vhi) << 16) | (unsigned)f2bf(vlo);
        *(unsigned*)((unsigned short*)outp + (size_t)node * C + 2 * lane) = p;
    } else {
        float vlo = act ? (acc_lo + bias[2 * lane])     : -INFINITY;
        float vhi = act ? (acc_hi + bias[2 * lane + 1]) : -INFINITY;
        float m = fmaxf(vlo, vhi);
#pragma unroll
        for (int o = 32; o > 0; o >>= 1) m = fmaxf(m, __shfl_xor(m, o));
        float ex = act ? (__expf(vlo - m) + __expf(vhi - m)) : 0.f;
        float ssum = ex;
#pragma unroll
        for (int o = 32; o > 0; o >>= 1) ssum += __shfl_xor(ssum, o);
        float lg = logf(ssum);
        if (act) {
            float2 o2 = make_float2(vlo - m - lg, vhi - m - lg);
            *(float2*)((float*)outp + (size_t)node * C + 2 * lane) = o2;
        }
    }
}

extern "C" void kernel_launch(void* const* d_in, const int* in_sizes, int n_in,
                              void* d_out, int out_size, void* d_ws, size_t ws_size,
                              hipStream_t stream)
{
    const float* x    = (const float*)d_in[0];
    const int*   ei   = (const int*)d_in[1];
    const float* W1   = (const float*)d_in[2];
    const float* atl1 = (const float*)d_in[3];
    const float* atr1 = (const float*)d_in[4];
    const float* b1   = (const float*)d_in[5];
    const float* W2   = (const float*)d_in[6];
    const float* atl2 = (const float*)d_in[7];
    const float* atr2 = (const float*)d_in[8];
    const float* b2   = (const float*)d_in[9];
    float* out = (float*)d_out;
    const int* src = ei;
    const int* dst = ei + N_EDGES;
    (void)ws_size; (void)n_in; (void)in_sizes; (void)out_size;

    // workspace layout (~68.5 MB)
    char* wsb = (char*)d_ws;
    unsigned short* xlb  = (unsigned short*)wsb;                       // 25.6 MB
    unsigned short* hb   = xlb + (size_t)N_NODES * HID_C;              // 25.6 MB (aliased by rank[] during CSR build)
    unsigned short* xl2b = hb  + (size_t)N_NODES * HID_C;              // 8 MB
    float* al1 = (float*)(xl2b + (size_t)N_NODES * OUT_C);
    float* ar1 = al1 + N_NODES;
    float* al2 = ar1 + N_NODES;
    float* ar2 = al2 + N_NODES;
    unsigned* cnt       = (unsigned*)(ar2 + N_NODES);
    unsigned* partial   = cnt + N_NODES;
    unsigned* blocksum  = partial + N_NODES;        // 512 slots
    unsigned* row_start = blocksum + 512;
    int*      csr_src   = (int*)(row_start + N_NODES);                 // 6.4 MB
    unsigned short* W1b = (unsigned short*)(csr_src + N_EDGES);        // 64 KB
    unsigned short* W2b = W1b + HID_C * IN_C;                          // 12 KB
    unsigned* rank = (unsigned*)hb;   // CSR-build-phase only; hb written later

    const int EB4 = (N_EDGES / 4 + 255) / 256;
    const int NB4 = (N_NODES + 3) / 4;

    // ---- CSR build: single atomic pass ----
    zero_cnt_kernel<<<NB1, 256, 0, stream>>>(cnt);
    rank_kernel<<<EB4, 256, 0, stream>>>(dst, cnt, rank);
    scan1_kernel<<<NB1, 256, 0, stream>>>(cnt, partial, blocksum);
    scan2_kernel<<<1, 512, 0, stream>>>(blocksum);
    scan3_kernel<<<NB1, 256, 0, stream>>>(partial, blocksum, row_start);
    place_kernel<<<EB4, 256, 0, stream>>>(src, dst, rank, row_start, csr_src);

    // ---- weight prep (bf16) ----
    prep_w_kernel<IN_C, HID_C><<<(HID_C * IN_C + 255) / 256, 256, 0, stream>>>(W1, W1b, HID_C);
    prep_w_kernel<HID_C, 48><<<(48 * HID_C + 255) / 256, 256, 0, stream>>>(W2, W2b, OUT_C);

    // ---- layer 1 ----
    gemm1_mfma_kernel<<<(N_NODES + 63) / 64, 256, 0, stream>>>(x, W1b, xlb);
    alphas_kernel<HID_C><<<NB4, 256, 0, stream>>>(xlb, atl1, atr1, al1, ar1);
    agg_kernel<HID_C, 0><<<NB4, 256, 0, stream>>>(
        csr_src, row_start, cnt, al1, ar1, xlb, b1, hb);

    // ---- layer 2 ----
    gemm2_mfma_kernel<<<(N_NODES + 63) / 64, 256, 0, stream>>>(hb, W2b, xl2b);
    alphas_kernel<OUT_C><<<NB4, 256, 0, stream>>>(xl2b, atl2, atr2, al2, ar2);
    agg_kernel<OUT_C, 1><<<NB4, 256, 0, stream>>>(
        csr_src, row_start, cnt, al2, ar2, xl2b, b2, out);
}

// Round 16
// 511.815 us; speedup vs baseline: 3.1131x; 1.0377x over previous
//
#include <hip/hip_runtime.h>
#include <hip/hip_bf16.h>

#define N_NODES 100000
#define N_EDGES 1600000
#define IN_C 256
#define HID_C 128
#define OUT_C 40
#define NB1 391   // ceil(N_NODES/256)

typedef short bf16x8 __attribute__((ext_vector_type(8)));
typedef float f32x4 __attribute__((ext_vector_type(4)));

// ---------- helpers ----------
__device__ __forceinline__ float lrelu(float x) { return x > 0.f ? x : 0.2f * x; }
__device__ __forceinline__ float eluf(float x) { return x > 0.f ? x : expm1f(x); }
__device__ __forceinline__ unsigned short f2bf(float f) {
    unsigned u = __float_as_uint(f);
    unsigned r = (u + 0x7FFFu + ((u >> 16) & 1u)) >> 16;
    return (unsigned short)r;
}
__device__ __forceinline__ float bf_lo(unsigned u) { return __uint_as_float(u << 16); }
__device__ __forceinline__ float bf_hi(unsigned u) { return __uint_as_float(u & 0xFFFF0000u); }

// ---------- zero the degree counters ----------
__global__ __launch_bounds__(256) void zero_cnt_kernel(unsigned* __restrict__ cnt)
{
    int i = blockIdx.x * 256 + threadIdx.x;
    if (i < N_NODES) cnt[i] = 0u;
}

// ---------- rank pass: the ONLY atomic pass ----------
__global__ __launch_bounds__(256) void rank_kernel(const int* __restrict__ dst,
                                                   unsigned* __restrict__ cnt,
                                                   unsigned* __restrict__ rank)
{
    int e4 = (blockIdx.x * 256 + threadIdx.x) * 4;
    if (e4 >= N_EDGES) return;
    int4 d = *(const int4*)(dst + e4);
    uint4 r;
    r.x = atomicAdd(&cnt[d.x], 1u);
    r.y = atomicAdd(&cnt[d.y], 1u);
    r.z = atomicAdd(&cnt[d.z], 1u);
    r.w = atomicAdd(&cnt[d.w], 1u);
    *(uint4*)(rank + e4) = r;
}

// ---------- scan level 1 ----------
__global__ __launch_bounds__(256) void scan1_kernel(const unsigned* __restrict__ cnt,
                                                    unsigned* __restrict__ partial,
                                                    unsigned* __restrict__ blocksum)
{
    int gid = blockIdx.x * 256 + threadIdx.x;
    unsigned v = (gid < N_NODES) ? cnt[gid] : 0u;
    unsigned orig = v;
    int lane = threadIdx.x & 63, w = threadIdx.x >> 6;
#pragma unroll
    for (int o = 1; o < 64; o <<= 1) {
        unsigned t = __shfl_up(v, o);
        if (lane >= o) v += t;
    }
    __shared__ unsigned wsum[4];
    if (lane == 63) wsum[w] = v;
    __syncthreads();
    unsigned off = 0;
    for (int i = 0; i < w; ++i) off += wsum[i];
    v += off;
    if (gid < N_NODES) partial[gid] = v - orig;
    if (threadIdx.x == 255) blocksum[blockIdx.x] = v;
}

// ---------- scan level 2 (one block) ----------
__global__ __launch_bounds__(512) void scan2_kernel(unsigned* __restrict__ blocksum)
{
    int tid = threadIdx.x;
    unsigned v = (tid < NB1) ? blocksum[tid] : 0u;
    unsigned orig = v;
    int lane = tid & 63, w = tid >> 6;
#pragma unroll
    for (int o = 1; o < 64; o <<= 1) {
        unsigned t = __shfl_up(v, o);
        if (lane >= o) v += t;
    }
    __shared__ unsigned wsum[8];
    if (lane == 63) wsum[w] = v;
    __syncthreads();
    unsigned off = 0;
    for (int i = 0; i < w; ++i) off += wsum[i];
    v += off;
    if (tid < NB1) blocksum[tid] = v - orig;
}

// ---------- scan level 3 ----------
__global__ __launch_bounds__(256) void scan3_kernel(const unsigned* __restrict__ partial,
                                                    const unsigned* __restrict__ blocksum,
                                                    unsigned* __restrict__ row_start)
{
    int gid = blockIdx.x * 256 + threadIdx.x;
    if (gid < N_NODES) row_start[gid] = partial[gid] + blocksum[gid >> 8];
}

// ---------- place edges into CSR: NO atomics ----------
__global__ __launch_bounds__(256) void place_kernel(const int* __restrict__ src,
                                                    const int* __restrict__ dst,
                                                    const unsigned* __restrict__ rank,
                                                    const unsigned* __restrict__ row_start,
                                                    int* __restrict__ csr_src)
{
    int e4 = (blockIdx.x * 256 + threadIdx.x) * 4;
    if (e4 >= N_EDGES) return;
    int4 d = *(const int4*)(dst + e4);
    int4 s = *(const int4*)(src + e4);
    uint4 r = *(const uint4*)(rank + e4);
    csr_src[row_start[d.x] + r.x] = s.x;
    csr_src[row_start[d.y] + r.y] = s.y;
    csr_src[row_start[d.z] + r.z] = s.z;
    csr_src[row_start[d.w] + r.w] = s.w;
}

// ---------- weight prep: fp32 [realC][KD] -> bf16 [PC][KD], zero-padded ----------
template <int KD, int PC>
__global__ __launch_bounds__(256) void prep_w_kernel(const float* __restrict__ W,
                                                     unsigned short* __restrict__ Wb,
                                                     int realC)
{
    int idx = blockIdx.x * 256 + threadIdx.x;
    if (idx >= PC * KD) return;
    int ch = idx / KD;
    int k = idx & (KD - 1);
    float v = (ch < realC) ? W[(size_t)ch * KD + k] : 0.f;
    Wb[idx] = f2bf(v);
}

// ---------- GEMM1 (MFMA, 2 row-frags/wave + K-prefetch) ----------
// xlb[N][128](bf16) = x[N][256](fp32->bf16) @ W1b[128][256]^T
// block = 256 thr = 4 waves; wave = 32 rows x 128 cols; grid = ceil(N/128)
__global__ __launch_bounds__(256) void gemm1_mfma_kernel(
    const float* __restrict__ A, const unsigned short* __restrict__ Wb,
    unsigned short* __restrict__ outb)
{
    const int KD = IN_C, NT = 8, COLS = HID_C;
    int tid = threadIdx.x;
    int wv = tid >> 6, lane = tid & 63;
    int bm = blockIdx.x * 128 + wv * 32;
    int r = lane & 15;
    int kg = lane >> 4;

    f32x4 acc[2][NT];
#pragma unroll
    for (int g = 0; g < 2; ++g)
#pragma unroll
        for (int n = 0; n < NT; ++n) acc[g][n] = (f32x4){0.f, 0.f, 0.f, 0.f};

    int arow0 = bm + r;       if (arow0 >= N_NODES) arow0 = N_NODES - 1;
    int arow1 = bm + 16 + r;  if (arow1 >= N_NODES) arow1 = N_NODES - 1;
    const float* ap0 = A + (size_t)arow0 * KD + kg * 8;
    const float* ap1 = A + (size_t)arow1 * KD + kg * 8;
    const unsigned short* bp = Wb + (size_t)r * KD + kg * 8;

    float4 c00 = *(const float4*)(ap0);
    float4 c01 = *(const float4*)(ap0 + 4);
    float4 c10 = *(const float4*)(ap1);
    float4 c11 = *(const float4*)(ap1 + 4);

    for (int ks = 0; ks < KD / 32; ++ks) {
        float4 n00, n01, n10, n11;
        if (ks + 1 < KD / 32) {
            n00 = *(const float4*)(ap0 + 32); n01 = *(const float4*)(ap0 + 36);
            n10 = *(const float4*)(ap1 + 32); n11 = *(const float4*)(ap1 + 36);
        }
        bf16x8 af0, af1;
        af0[0] = (short)f2bf(c00.x); af0[1] = (short)f2bf(c00.y);
        af0[2] = (short)f2bf(c00.z); af0[3] = (short)f2bf(c00.w);
        af0[4] = (short)f2bf(c01.x); af0[5] = (short)f2bf(c01.y);
        af0[6] = (short)f2bf(c01.z); af0[7] = (short)f2bf(c01.w);
        af1[0] = (short)f2bf(c10.x); af1[1] = (short)f2bf(c10.y);
        af1[2] = (short)f2bf(c10.z); af1[3] = (short)f2bf(c10.w);
        af1[4] = (short)f2bf(c11.x); af1[5] = (short)f2bf(c11.y);
        af1[6] = (short)f2bf(c11.z); af1[7] = (short)f2bf(c11.w);
#pragma unroll
        for (int n = 0; n < NT; ++n) {
            bf16x8 bf_ = *(const bf16x8*)(bp + (size_t)n * 16 * KD);
            acc[0][n] = __builtin_amdgcn_mfma_f32_16x16x32_bf16(af0, bf_, acc[0][n], 0, 0, 0);
            acc[1][n] = __builtin_amdgcn_mfma_f32_16x16x32_bf16(af1, bf_, acc[1][n], 0, 0, 0);
        }
        c00 = n00; c01 = n01; c10 = n10; c11 = n11;
        ap0 += 32; ap1 += 32; bp += 32;
    }

#pragma unroll
    for (int g = 0; g < 2; ++g)
#pragma unroll
        for (int n = 0; n < NT; ++n) {
            int col = n * 16 + r;
#pragma unroll
            for (int rr = 0; rr < 4; ++rr) {
                int node = bm + g * 16 + kg * 4 + rr;
                if (node < N_NODES) outb[(size_t)node * COLS + col] = f2bf(acc[g][n][rr]);
            }
        }
}

// ---------- GEMM2 (MFMA): xl2b[N][40](bf16) = h[N][128](bf16) @ W2b[48][128]^T ----------
__global__ __launch_bounds__(256) void gemm2_mfma_kernel(
    const unsigned short* __restrict__ Ab, const unsigned short* __restrict__ Wb,
    unsigned short* __restrict__ outb)
{
    const int KD = HID_C, NT = 3, COLS = OUT_C;
    int tid = threadIdx.x;
    int wv = tid >> 6, lane = tid & 63;
    int bm = blockIdx.x * 64 + wv * 16;
    int r = lane & 15;
    int kg = lane >> 4;

    f32x4 acc[NT];
#pragma unroll
    for (int n = 0; n < NT; ++n) acc[n] = (f32x4){0.f, 0.f, 0.f, 0.f};

    int arow = bm + r; if (arow >= N_NODES) arow = N_NODES - 1;
    const unsigned short* ap = Ab + (size_t)arow * KD + kg * 8;
    const unsigned short* bp = Wb + (size_t)r * KD + kg * 8;

    for (int ks = 0; ks < KD / 32; ++ks) {
        bf16x8 af = *(const bf16x8*)(ap);
#pragma unroll
        for (int n = 0; n < NT; ++n) {
            bf16x8 bf_ = *(const bf16x8*)(bp + (size_t)n * 16 * KD);
            acc[n] = __builtin_amdgcn_mfma_f32_16x16x32_bf16(af, bf_, acc[n], 0, 0, 0);
        }
        ap += 32; bp += 32;
    }

#pragma unroll
    for (int n = 0; n < NT; ++n) {
        int col = n * 16 + r;
        if (col < COLS) {
#pragma unroll
            for (int rr = 0; rr < 4; ++rr) {
                int node = bm + kg * 4 + rr;
                if (node < N_NODES) outb[(size_t)node * COLS + col] = f2bf(acc[n][rr]);
            }
        }
    }
}

// ---------- per-node attention scalars (bf16 features) ----------
template <int C>
__global__ __launch_bounds__(256) void alphas_kernel(
    const unsigned short* __restrict__ xlb, const float* __restrict__ attl,
    const float* __restrict__ attr, float* __restrict__ al, float* __restrict__ ar)
{
    int wid = blockIdx.x * 4 + (threadIdx.x >> 6);
    int lane = threadIdx.x & 63;
    if (wid >= N_NODES) return;
    float sl = 0.f, sr = 0.f;
    if (2 * lane < C) {
        unsigned u = *(const unsigned*)(xlb + (size_t)wid * C + 2 * lane);
        float lo = bf_lo(u), hi = bf_hi(u);
        sl += lo * attl[2 * lane] + hi * attl[2 * lane + 1];
        sr += lo * attr[2 * lane] + hi * attr[2 * lane + 1];
    }
#pragma unroll
    for (int o = 32; o > 0; o >>= 1) { sl += __shfl_xor(sl, o); sr += __shfl_xor(sr, o); }
    if (lane == 0) { al[wid] = sl; ar[wid] = sr; }
}

// ---------- fused per-node aggregation (bf16 gather, register-held edge weights) ----------
// MODE 0: h[node][128](bf16) = elu(sum + b)   MODE 1: out[node][40](f32) = log_softmax(sum + b)
template <int C, int MODE>
__global__ __launch_bounds__(256) void agg_kernel(
    const int* __restrict__ csr_src,
    const unsigned* __restrict__ row_start, const unsigned* __restrict__ deg,
    const float* __restrict__ al, const float* __restrict__ ar,
    const unsigned short* __restrict__ xlb, const float* __restrict__ bias,
    void* __restrict__ outp)
{
    int node = blockIdx.x * 4 + (threadIdx.x >> 6);
    int lane = threadIdx.x & 63;
    if (node >= N_NODES) return;
    unsigned beg = row_start[node];
    unsigned dn  = deg[node];
    unsigned end = beg + dn;
    float ar_d = ar[node];

    // ---- stats pass: lane j owns edge beg+j (first 64); keeps s_l and w_l in regs ----
    unsigned i0 = beg + lane;
    int   s_l = (i0 < end) ? csr_src[i0] : 0;
    float e0  = (i0 < end) ? lrelu(al[s_l] + ar_d) : -INFINITY;
    float m_l = e0;
    for (unsigned i = i0 + 64; i < end; i += 64)
        m_l = fmaxf(m_l, lrelu(al[csr_src[i]] + ar_d));
    float mx = m_l;
#pragma unroll
    for (int o = 32; o > 0; o >>= 1) mx = fmaxf(mx, __shfl_xor(mx, o));
    float w_l = (i0 < end) ? __expf(e0 - mx) : 0.f;
    float s_sum = w_l;
    for (unsigned i = i0 + 64; i < end; i += 64)
        s_sum += __expf(lrelu(al[csr_src[i]] + ar_d) - mx);
    float sm = s_sum;
#pragma unroll
    for (int o = 32; o > 0; o >>= 1) sm += __shfl_xor(sm, o);
    float inv = 1.f / fmaxf(sm, 1e-16f);

    // ---- weighted gather: broadcast (s_j, w_j) from registers via shfl ----
    constexpr bool FULL = (C >= 128);          // all 64 lanes own a dword
    const bool act = FULL || (2 * lane < C);
    float acc_lo = 0.f, acc_hi = 0.f;
    int nfast = (int)(dn < 64u ? dn : 64u);    // wave-uniform
    int j = 0;
    for (; j + 4 <= nfast; j += 4) {
        float w0 = __shfl(w_l, j),     w1 = __shfl(w_l, j + 1);
        float w2 = __shfl(w_l, j + 2), w3 = __shfl(w_l, j + 3);
        int   s0 = __shfl(s_l, j),     s1 = __shfl(s_l, j + 1);
        int   s2 = __shfl(s_l, j + 2), s3 = __shfl(s_l, j + 3);
        if (act) {
            unsigned u0 = *(const unsigned*)(xlb + (size_t)s0 * C + 2 * lane);
            unsigned u1 = *(const unsigned*)(xlb + (size_t)s1 * C + 2 * lane);
            unsigned u2 = *(const unsigned*)(xlb + (size_t)s2 * C + 2 * lane);
            unsigned u3 = *(const unsigned*)(xlb + (size_t)s3 * C + 2 * lane);
            acc_lo += bf_lo(u0) * w0 + bf_lo(u1) * w1 + bf_lo(u2) * w2 + bf_lo(u3) * w3;
            acc_hi += bf_hi(u0) * w0 + bf_hi(u1) * w1 + bf_hi(u2) * w2 + bf_hi(u3) * w3;
        }
    }
    for (; j < nfast; ++j) {
        float w0 = __shfl(w_l, j);
        int   s0 = __shfl(s_l, j);
        if (act) {
            unsigned u0 = *(const unsigned*)(xlb + (size_t)s0 * C + 2 * lane);
            acc_lo += bf_lo(u0) * w0;
            acc_hi += bf_hi(u0) * w0;
        }
    }
    // rare tail: deg > 64 -> recompute weights (wave-uniform branch)
    for (unsigned i = beg + 64; i < end; ++i) {
        int s0 = csr_src[i];
        float w0 = __expf(lrelu(al[s0] + ar_d) - mx);
        if (act) {
            unsigned u0 = *(const unsigned*)(xlb + (size_t)s0 * C + 2 * lane);
            acc_lo += bf_lo(u0) * w0;
            acc_hi += bf_hi(u0) * w0;
        }
    }
    acc_lo *= inv; acc_hi *= inv;

    if (MODE == 0) {
        float vlo = eluf(acc_lo + bias[2 * lane]);
        float vhi = eluf(acc_hi + bias[2 * lane + 1]);
        unsigned p = ((unsigned)f2bf(vhi) << 16) | (unsigned)f2bf(vlo);
        *(unsigned*)((unsigned short*)outp + (size_t)node * C + 2 * lane) = p;
    } else {
        float vlo = act ? (acc_lo + bias[2 * lane])     : -INFINITY;
        float vhi = act ? (acc_hi + bias[2 * lane + 1]) : -INFINITY;
        float m = fmaxf(vlo, vhi);
#pragma unroll
        for (int o = 32; o > 0; o >>= 1) m = fmaxf(m, __shfl_xor(m, o));
        float ex = act ? (__expf(vlo - m) + __expf(vhi - m)) : 0.f;
        float ssum = ex;
#pragma unroll
        for (int o = 32; o > 0; o >>= 1) ssum += __shfl_xor(ssum, o);
        float lg = logf(ssum);
        if (act) {
            float2 o2 = make_float2(vlo - m - lg, vhi - m - lg);
            *(float2*)((float*)outp + (size_t)node * C + 2 * lane) = o2;
        }
    }
}

extern "C" void kernel_launch(void* const* d_in, const int* in_sizes, int n_in,
                              void* d_out, int out_size, void* d_ws, size_t ws_size,
                              hipStream_t stream)
{
    const float* x    = (const float*)d_in[0];
    const int*   ei   = (const int*)d_in[1];
    const float* W1   = (const float*)d_in[2];
    const float* atl1 = (const float*)d_in[3];
    const float* atr1 = (const float*)d_in[4];
    const float* b1   = (const float*)d_in[5];
    const float* W2   = (const float*)d_in[6];
    const float* atl2 = (const float*)d_in[7];
    const float* atr2 = (const float*)d_in[8];
    const float* b2   = (const float*)d_in[9];
    float* out = (float*)d_out;
    const int* src = ei;
    const int* dst = ei + N_EDGES;
    (void)ws_size; (void)n_in; (void)in_sizes; (void)out_size;

    // workspace layout (~68.5 MB)
    char* wsb = (char*)d_ws;
    unsigned short* xlb  = (unsigned short*)wsb;                       // 25.6 MB
    unsigned short* hb   = xlb + (size_t)N_NODES * HID_C;              // 25.6 MB (aliased by rank[] during CSR build)
    unsigned short* xl2b = hb  + (size_t)N_NODES * HID_C;              // 8 MB
    float* al1 = (float*)(xl2b + (size_t)N_NODES * OUT_C);
    float* ar1 = al1 + N_NODES;
    float* al2 = ar1 + N_NODES;
    float* ar2 = al2 + N_NODES;
    unsigned* cnt       = (unsigned*)(ar2 + N_NODES);
    unsigned* partial   = cnt + N_NODES;
    unsigned* blocksum  = partial + N_NODES;        // 512 slots
    unsigned* row_start = blocksum + 512;
    int*      csr_src   = (int*)(row_start + N_NODES);                 // 6.4 MB
    unsigned short* W1b = (unsigned short*)(csr_src + N_EDGES);        // 64 KB
    unsigned short* W2b = W1b + HID_C * IN_C;                          // 12 KB
    unsigned* rank = (unsigned*)hb;   // CSR-build-phase only; hb written later

    const int EB4 = (N_EDGES / 4 + 255) / 256;
    const int NB4 = (N_NODES + 3) / 4;

    // ---- CSR build: single atomic pass ----
    zero_cnt_kernel<<<NB1, 256, 0, stream>>>(cnt);
    rank_kernel<<<EB4, 256, 0, stream>>>(dst, cnt, rank);
    scan1_kernel<<<NB1, 256, 0, stream>>>(cnt, partial, blocksum);
    scan2_kernel<<<1, 512, 0, stream>>>(blocksum);
    scan3_kernel<<<NB1, 256, 0, stream>>>(partial, blocksum, row_start);
    place_kernel<<<EB4, 256, 0, stream>>>(src, dst, rank, row_start, csr_src);

    // ---- weight prep (bf16) ----
    prep_w_kernel<IN_C, HID_C><<<(HID_C * IN_C + 255) / 256, 256, 0, stream>>>(W1, W1b, HID_C);
    prep_w_kernel<HID_C, 48><<<(48 * HID_C + 255) / 256, 256, 0, stream>>>(W2, W2b, OUT_C);

    // ---- layer 1 ----
    gemm1_mfma_kernel<<<(N_NODES + 127) / 128, 256, 0, stream>>>(x, W1b, xlb);
    alphas_kernel<HID_C><<<NB4, 256, 0, stream>>>(xlb, atl1, atr1, al1, ar1);
    agg_kernel<HID_C, 0><<<NB4, 256, 0, stream>>>(
        csr_src, row_start, cnt, al1, ar1, xlb, b1, hb);

    // ---- layer 2 ----
    gemm2_mfma_kernel<<<(N_NODES + 63) / 64, 256, 0, stream>>>(hb, W2b, xl2b);
    alphas_kernel<OUT_C><<<NB4, 256, 0, stream>>>(xl2b, atl2, atr2, al2, ar2);
    agg_kernel<OUT_C, 1><<<NB4, 256, 0, stream>>>(
        csr_src, row_start, cnt, al2, ar2, xl2b, b2, out);
}

// Round 17
// 483.532 us; speedup vs baseline: 3.2952x; 1.0585x over previous
//
#include <hip/hip_runtime.h>
#include <hip/hip_bf16.h>

#define N_NODES 100000
#define N_EDGES 1600000
#define IN_C 256
#define HID_C 128
#define OUT_C 40
#define NB1 391   // ceil(N_NODES/256)

typedef short bf16x8 __attribute__((ext_vector_type(8)));
typedef float f32x4 __attribute__((ext_vector_type(4)));

// ---------- helpers ----------
__device__ __forceinline__ float lrelu(float x) { return x > 0.f ? x : 0.2f * x; }
__device__ __forceinline__ float eluf(float x) { return x > 0.f ? x : expm1f(x); }
__device__ __forceinline__ unsigned short f2bf(float f) {
    unsigned u = __float_as_uint(f);
    unsigned r = (u + 0x7FFFu + ((u >> 16) & 1u)) >> 16;
    return (unsigned short)r;
}
__device__ __forceinline__ float bf_lo(unsigned u) { return __uint_as_float(u << 16); }
__device__ __forceinline__ float bf_hi(unsigned u) { return __uint_as_float(u & 0xFFFF0000u); }

// ---------- zero the degree counters ----------
__global__ __launch_bounds__(256) void zero_cnt_kernel(unsigned* __restrict__ cnt)
{
    int i = blockIdx.x * 256 + threadIdx.x;
    if (i < N_NODES) cnt[i] = 0u;
}

// ---------- rank pass: the ONLY atomic pass ----------
__global__ __launch_bounds__(256) void rank_kernel(const int* __restrict__ dst,
                                                   unsigned* __restrict__ cnt,
                                                   unsigned* __restrict__ rank)
{
    int e4 = (blockIdx.x * 256 + threadIdx.x) * 4;
    if (e4 >= N_EDGES) return;
    int4 d = *(const int4*)(dst + e4);
    uint4 r;
    r.x = atomicAdd(&cnt[d.x], 1u);
    r.y = atomicAdd(&cnt[d.y], 1u);
    r.z = atomicAdd(&cnt[d.z], 1u);
    r.w = atomicAdd(&cnt[d.w], 1u);
    *(uint4*)(rank + e4) = r;
}

// ---------- scan level 1 ----------
__global__ __launch_bounds__(256) void scan1_kernel(const unsigned* __restrict__ cnt,
                                                    unsigned* __restrict__ partial,
                                                    unsigned* __restrict__ blocksum)
{
    int gid = blockIdx.x * 256 + threadIdx.x;
    unsigned v = (gid < N_NODES) ? cnt[gid] : 0u;
    unsigned orig = v;
    int lane = threadIdx.x & 63, w = threadIdx.x >> 6;
#pragma unroll
    for (int o = 1; o < 64; o <<= 1) {
        unsigned t = __shfl_up(v, o);
        if (lane >= o) v += t;
    }
    __shared__ unsigned wsum[4];
    if (lane == 63) wsum[w] = v;
    __syncthreads();
    unsigned off = 0;
    for (int i = 0; i < w; ++i) off += wsum[i];
    v += off;
    if (gid < N_NODES) partial[gid] = v - orig;
    if (threadIdx.x == 255) blocksum[blockIdx.x] = v;
}

// ---------- scan level 2 (one block) ----------
__global__ __launch_bounds__(512) void scan2_kernel(unsigned* __restrict__ blocksum)
{
    int tid = threadIdx.x;
    unsigned v = (tid < NB1) ? blocksum[tid] : 0u;
    unsigned orig = v;
    int lane = tid & 63, w = tid >> 6;
#pragma unroll
    for (int o = 1; o < 64; o <<= 1) {
        unsigned t = __shfl_up(v, o);
        if (lane >= o) v += t;
    }
    __shared__ unsigned wsum[8];
    if (lane == 63) wsum[w] = v;
    __syncthreads();
    unsigned off = 0;
    for (int i = 0; i < w; ++i) off += wsum[i];
    v += off;
    if (tid < NB1) blocksum[tid] = v - orig;
}

// ---------- scan level 3 ----------
__global__ __launch_bounds__(256) void scan3_kernel(const unsigned* __restrict__ partial,
                                                    const unsigned* __restrict__ blocksum,
                                                    unsigned* __restrict__ row_start)
{
    int gid = blockIdx.x * 256 + threadIdx.x;
    if (gid < N_NODES) row_start[gid] = partial[gid] + blocksum[gid >> 8];
}

// ---------- place edges into CSR: NO atomics ----------
__global__ __launch_bounds__(256) void place_kernel(const int* __restrict__ src,
                                                    const int* __restrict__ dst,
                                                    const unsigned* __restrict__ rank,
                                                    const unsigned* __restrict__ row_start,
                                                    int* __restrict__ csr_src)
{
    int e4 = (blockIdx.x * 256 + threadIdx.x) * 4;
    if (e4 >= N_EDGES) return;
    int4 d = *(const int4*)(dst + e4);
    int4 s = *(const int4*)(src + e4);
    uint4 r = *(const uint4*)(rank + e4);
    csr_src[row_start[d.x] + r.x] = s.x;
    csr_src[row_start[d.y] + r.y] = s.y;
    csr_src[row_start[d.z] + r.z] = s.z;
    csr_src[row_start[d.w] + r.w] = s.w;
}

// ---------- weight prep: fp32 [realC][KD] -> bf16 [PC][KD], zero-padded ----------
template <int KD, int PC>
__global__ __launch_bounds__(256) void prep_w_kernel(const float* __restrict__ W,
                                                     unsigned short* __restrict__ Wb,
                                                     int realC)
{
    int idx = blockIdx.x * 256 + threadIdx.x;
    if (idx >= PC * KD) return;
    int ch = idx / KD;
    int k = idx & (KD - 1);
    float v = (ch < realC) ? W[(size_t)ch * KD + k] : 0.f;
    Wb[idx] = f2bf(v);
}

// ---------- GEMM1 (MFMA, 2 row-frags/wave + K-prefetch) ----------
__global__ __launch_bounds__(256) void gemm1_mfma_kernel(
    const float* __restrict__ A, const unsigned short* __restrict__ Wb,
    unsigned short* __restrict__ outb)
{
    const int KD = IN_C, NT = 8, COLS = HID_C;
    int tid = threadIdx.x;
    int wv = tid >> 6, lane = tid & 63;
    int bm = blockIdx.x * 128 + wv * 32;
    int r = lane & 15;
    int kg = lane >> 4;

    f32x4 acc[2][NT];
#pragma unroll
    for (int g = 0; g < 2; ++g)
#pragma unroll
        for (int n = 0; n < NT; ++n) acc[g][n] = (f32x4){0.f, 0.f, 0.f, 0.f};

    int arow0 = bm + r;       if (arow0 >= N_NODES) arow0 = N_NODES - 1;
    int arow1 = bm + 16 + r;  if (arow1 >= N_NODES) arow1 = N_NODES - 1;
    const float* ap0 = A + (size_t)arow0 * KD + kg * 8;
    const float* ap1 = A + (size_t)arow1 * KD + kg * 8;
    const unsigned short* bp = Wb + (size_t)r * KD + kg * 8;

    float4 c00 = *(const float4*)(ap0);
    float4 c01 = *(const float4*)(ap0 + 4);
    float4 c10 = *(const float4*)(ap1);
    float4 c11 = *(const float4*)(ap1 + 4);

    for (int ks = 0; ks < KD / 32; ++ks) {
        float4 n00, n01, n10, n11;
        if (ks + 1 < KD / 32) {
            n00 = *(const float4*)(ap0 + 32); n01 = *(const float4*)(ap0 + 36);
            n10 = *(const float4*)(ap1 + 32); n11 = *(const float4*)(ap1 + 36);
        }
        bf16x8 af0, af1;
        af0[0] = (short)f2bf(c00.x); af0[1] = (short)f2bf(c00.y);
        af0[2] = (short)f2bf(c00.z); af0[3] = (short)f2bf(c00.w);
        af0[4] = (short)f2bf(c01.x); af0[5] = (short)f2bf(c01.y);
        af0[6] = (short)f2bf(c01.z); af0[7] = (short)f2bf(c01.w);
        af1[0] = (short)f2bf(c10.x); af1[1] = (short)f2bf(c10.y);
        af1[2] = (short)f2bf(c10.z); af1[3] = (short)f2bf(c10.w);
        af1[4] = (short)f2bf(c11.x); af1[5] = (short)f2bf(c11.y);
        af1[6] = (short)f2bf(c11.z); af1[7] = (short)f2bf(c11.w);
#pragma unroll
        for (int n = 0; n < NT; ++n) {
            bf16x8 bf_ = *(const bf16x8*)(bp + (size_t)n * 16 * KD);
            acc[0][n] = __builtin_amdgcn_mfma_f32_16x16x32_bf16(af0, bf_, acc[0][n], 0, 0, 0);
            acc[1][n] = __builtin_amdgcn_mfma_f32_16x16x32_bf16(af1, bf_, acc[1][n], 0, 0, 0);
        }
        c00 = n00; c01 = n01; c10 = n10; c11 = n11;
        ap0 += 32; ap1 += 32; bp += 32;
    }

#pragma unroll
    for (int g = 0; g < 2; ++g)
#pragma unroll
        for (int n = 0; n < NT; ++n) {
            int col = n * 16 + r;
#pragma unroll
            for (int rr = 0; rr < 4; ++rr) {
                int node = bm + g * 16 + kg * 4 + rr;
                if (node < N_NODES) outb[(size_t)node * COLS + col] = f2bf(acc[g][n][rr]);
            }
        }
}

// ---------- GEMM2 (MFMA): xl2b[N][40](bf16) = h[N][128](bf16) @ W2b[48][128]^T ----------
__global__ __launch_bounds__(256) void gemm2_mfma_kernel(
    const unsigned short* __restrict__ Ab, const unsigned short* __restrict__ Wb,
    unsigned short* __restrict__ outb)
{
    const int KD = HID_C, NT = 3, COLS = OUT_C;
    int tid = threadIdx.x;
    int wv = tid >> 6, lane = tid & 63;
    int bm = blockIdx.x * 64 + wv * 16;
    int r = lane & 15;
    int kg = lane >> 4;

    f32x4 acc[NT];
#pragma unroll
    for (int n = 0; n < NT; ++n) acc[n] = (f32x4){0.f, 0.f, 0.f, 0.f};

    int arow = bm + r; if (arow >= N_NODES) arow = N_NODES - 1;
    const unsigned short* ap = Ab + (size_t)arow * KD + kg * 8;
    const unsigned short* bp = Wb + (size_t)r * KD + kg * 8;

    for (int ks = 0; ks < KD / 32; ++ks) {
        bf16x8 af = *(const bf16x8*)(ap);
#pragma unroll
        for (int n = 0; n < NT; ++n) {
            bf16x8 bf_ = *(const bf16x8*)(bp + (size_t)n * 16 * KD);
            acc[n] = __builtin_amdgcn_mfma_f32_16x16x32_bf16(af, bf_, acc[n], 0, 0, 0);
        }
        ap += 32; bp += 32;
    }

#pragma unroll
    for (int n = 0; n < NT; ++n) {
        int col = n * 16 + r;
        if (col < COLS) {
#pragma unroll
            for (int rr = 0; rr < 4; ++rr) {
                int node = bm + kg * 4 + rr;
                if (node < N_NODES) outb[(size_t)node * COLS + col] = f2bf(acc[n][rr]);
            }
        }
    }
}

// ---------- per-node attention scalars (bf16 features) ----------
template <int C>
__global__ __launch_bounds__(256) void alphas_kernel(
    const unsigned short* __restrict__ xlb, const float* __restrict__ attl,
    const float* __restrict__ attr, float* __restrict__ al, float* __restrict__ ar)
{
    int wid = blockIdx.x * 4 + (threadIdx.x >> 6);
    int lane = threadIdx.x & 63;
    if (wid >= N_NODES) return;
    float sl = 0.f, sr = 0.f;
    if (2 * lane < C) {
        unsigned u = *(const unsigned*)(xlb + (size_t)wid * C + 2 * lane);
        float lo = bf_lo(u), hi = bf_hi(u);
        sl += lo * attl[2 * lane] + hi * attl[2 * lane + 1];
        sr += lo * attr[2 * lane] + hi * attr[2 * lane + 1];
    }
#pragma unroll
    for (int o = 32; o > 0; o >>= 1) { sl += __shfl_xor(sl, o); sr += __shfl_xor(sr, o); }
    if (lane == 0) { al[wid] = sl; ar[wid] = sr; }
}

// ---------- fused per-node aggregation (bf16 gather, group-of-G lanes per node) ----------
// MODE 0: h[node][128](bf16) = elu(sum + b)   MODE 1: out[node][40](f32) = log_softmax(sum + b)
// LG = log2(G). G=64 for C=128 (all lanes own a dword); G=32 for C=40 (2 nodes/wave).
template <int C, int MODE, int LG>
__global__ __launch_bounds__(256) void agg_kernel(
    const int* __restrict__ csr_src,
    const unsigned* __restrict__ row_start, const unsigned* __restrict__ deg,
    const float* __restrict__ al, const float* __restrict__ ar,
    const unsigned short* __restrict__ xlb, const float* __restrict__ bias,
    void* __restrict__ outp)
{
    constexpr int G = 1 << LG;
    constexpr int GPB = 256 >> LG;     // node-groups per block
    int node = blockIdx.x * GPB + (threadIdx.x >> LG);
    int hl = threadIdx.x & (G - 1);
    if (node >= N_NODES) return;
    unsigned beg = row_start[node];
    unsigned dn  = deg[node];
    unsigned end = beg + dn;
    float ar_d = ar[node];

    // ---- stats pass: lane j of group owns edge beg+j (first G); keeps s_l, w_l in regs ----
    unsigned i0 = beg + hl;
    int   s_l = (i0 < end) ? csr_src[i0] : 0;
    float e0  = (i0 < end) ? lrelu(al[s_l] + ar_d) : -INFINITY;
    float m_l = e0;
    for (unsigned i = i0 + G; i < end; i += G)
        m_l = fmaxf(m_l, lrelu(al[csr_src[i]] + ar_d));
    float mx = m_l;
#pragma unroll
    for (int o = G / 2; o > 0; o >>= 1) mx = fmaxf(mx, __shfl_xor(mx, o, G));
    float w_l = (i0 < end) ? __expf(e0 - mx) : 0.f;
    float s_sum = w_l;
    for (unsigned i = i0 + G; i < end; i += G)
        s_sum += __expf(lrelu(al[csr_src[i]] + ar_d) - mx);
    float sm = s_sum;
#pragma unroll
    for (int o = G / 2; o > 0; o >>= 1) sm += __shfl_xor(sm, o, G);
    float inv = 1.f / fmaxf(sm, 1e-16f);

    // ---- weighted gather: broadcast (s_j, w_j) within the group via width-G shfl ----
    constexpr bool FULL = (2 * (G - 1) < C);   // every group lane owns a dword
    const bool act = FULL || (2 * hl < C);
    float acc_lo = 0.f, acc_hi = 0.f;
    int nfast = (int)(dn < (unsigned)G ? dn : (unsigned)G);   // group-uniform
    int j = 0;
    for (; j + 4 <= nfast; j += 4) {
        float w0 = __shfl(w_l, j, G),     w1 = __shfl(w_l, j + 1, G);
        float w2 = __shfl(w_l, j + 2, G), w3 = __shfl(w_l, j + 3, G);
        int   s0 = __shfl(s_l, j, G),     s1 = __shfl(s_l, j + 1, G);
        int   s2 = __shfl(s_l, j + 2, G), s3 = __shfl(s_l, j + 3, G);
        if (act) {
            unsigned u0 = *(const unsigned*)(xlb + (size_t)s0 * C + 2 * hl);
            unsigned u1 = *(const unsigned*)(xlb + (size_t)s1 * C + 2 * hl);
            unsigned u2 = *(const unsigned*)(xlb + (size_t)s2 * C + 2 * hl);
            unsigned u3 = *(const unsigned*)(xlb + (size_t)s3 * C + 2 * hl);
            acc_lo += bf_lo(u0) * w0 + bf_lo(u1) * w1 + bf_lo(u2) * w2 + bf_lo(u3) * w3;
            acc_hi += bf_hi(u0) * w0 + bf_hi(u1) * w1 + bf_hi(u2) * w2 + bf_hi(u3) * w3;
        }
    }
    for (; j < nfast; ++j) {
        float w0 = __shfl(w_l, j, G);
        int   s0 = __shfl(s_l, j, G);
        if (act) {
            unsigned u0 = *(const unsigned*)(xlb + (size_t)s0 * C + 2 * hl);
            acc_lo += bf_lo(u0) * w0;
            acc_hi += bf_hi(u0) * w0;
        }
    }
    // rare tail: deg > G -> recompute weights (group-uniform branch)
    for (unsigned i = beg + G; i < end; ++i) {
        int s0 = csr_src[i];
        float w0 = __expf(lrelu(al[s0] + ar_d) - mx);
        if (act) {
            unsigned u0 = *(const unsigned*)(xlb + (size_t)s0 * C + 2 * hl);
            acc_lo += bf_lo(u0) * w0;
            acc_hi += bf_hi(u0) * w0;
        }
    }
    acc_lo *= inv; acc_hi *= inv;

    if (MODE == 0) {
        float vlo = eluf(acc_lo + bias[2 * hl]);
        float vhi = eluf(acc_hi + bias[2 * hl + 1]);
        unsigned p = ((unsigned)f2bf(vhi) << 16) | (unsigned)f2bf(vlo);
        *(unsigned*)((unsigned short*)outp + (size_t)node * C + 2 * hl) = p;
    } else {
        float vlo = act ? (acc_lo + bias[2 * hl])     : -INFINITY;
        float vhi = act ? (acc_hi + bias[2 * hl + 1]) : -INFINITY;
        float m = fmaxf(vlo, vhi);
#pragma unroll
        for (int o = G / 2; o > 0; o >>= 1) m = fmaxf(m, __shfl_xor(m, o, G));
        float ex = act ? (__expf(vlo - m) + __expf(vhi - m)) : 0.f;
        float ssum = ex;
#pragma unroll
        for (int o = G / 2; o > 0; o >>= 1) ssum += __shfl_xor(ssum, o, G);
        float lg = logf(ssum);
        if (act) {
            float2 o2 = make_float2(vlo - m - lg, vhi - m - lg);
            *(float2*)((float*)outp + (size_t)node * C + 2 * hl) = o2;
        }
    }
}

extern "C" void kernel_launch(void* const* d_in, const int* in_sizes, int n_in,
                              void* d_out, int out_size, void* d_ws, size_t ws_size,
                              hipStream_t stream)
{
    const float* x    = (const float*)d_in[0];
    const int*   ei   = (const int*)d_in[1];
    const float* W1   = (const float*)d_in[2];
    const float* atl1 = (const float*)d_in[3];
    const float* atr1 = (const float*)d_in[4];
    const float* b1   = (const float*)d_in[5];
    const float* W2   = (const float*)d_in[6];
    const float* atl2 = (const float*)d_in[7];
    const float* atr2 = (const float*)d_in[8];
    const float* b2   = (const float*)d_in[9];
    float* out = (float*)d_out;
    const int* src = ei;
    const int* dst = ei + N_EDGES;
    (void)ws_size; (void)n_in; (void)in_sizes; (void)out_size;

    // workspace layout (~68.5 MB)
    char* wsb = (char*)d_ws;
    unsigned short* xlb  = (unsigned short*)wsb;                       // 25.6 MB
    unsigned short* hb   = xlb + (size_t)N_NODES * HID_C;              // 25.6 MB (aliased by rank[] during CSR build)
    unsigned short* xl2b = hb  + (size_t)N_NODES * HID_C;              // 8 MB
    float* al1 = (float*)(xl2b + (size_t)N_NODES * OUT_C);
    float* ar1 = al1 + N_NODES;
    float* al2 = ar1 + N_NODES;
    float* ar2 = al2 + N_NODES;
    unsigned* cnt       = (unsigned*)(ar2 + N_NODES);
    unsigned* partial   = cnt + N_NODES;
    unsigned* blocksum  = partial + N_NODES;        // 512 slots
    unsigned* row_start = blocksum + 512;
    int*      csr_src   = (int*)(row_start + N_NODES);                 // 6.4 MB
    unsigned short* W1b = (unsigned short*)(csr_src + N_EDGES);        // 64 KB
    unsigned short* W2b = W1b + HID_C * IN_C;                          // 12 KB
    unsigned* rank = (unsigned*)hb;   // CSR-build-phase only; hb written later

    const int EB4 = (N_EDGES / 4 + 255) / 256;
    const int NB4 = (N_NODES + 3) / 4;
    const int NB8 = (N_NODES + 7) / 8;

    // ---- CSR build: single atomic pass ----
    zero_cnt_kernel<<<NB1, 256, 0, stream>>>(cnt);
    rank_kernel<<<EB4, 256, 0, stream>>>(dst, cnt, rank);
    scan1_kernel<<<NB1, 256, 0, stream>>>(cnt, partial, blocksum);
    scan2_kernel<<<1, 512, 0, stream>>>(blocksum);
    scan3_kernel<<<NB1, 256, 0, stream>>>(partial, blocksum, row_start);
    place_kernel<<<EB4, 256, 0, stream>>>(src, dst, rank, row_start, csr_src);

    // ---- weight prep (bf16) ----
    prep_w_kernel<IN_C, HID_C><<<(HID_C * IN_C + 255) / 256, 256, 0, stream>>>(W1, W1b, HID_C);
    prep_w_kernel<HID_C, 48><<<(48 * HID_C + 255) / 256, 256, 0, stream>>>(W2, W2b, OUT_C);

    // ---- layer 1 ----
    gemm1_mfma_kernel<<<(N_NODES + 127) / 128, 256, 0, stream>>>(x, W1b, xlb);
    alphas_kernel<HID_C><<<NB4, 256, 0, stream>>>(xlb, atl1, atr1, al1, ar1);
    agg_kernel<HID_C, 0, 6><<<NB4, 256, 0, stream>>>(
        csr_src, row_start, cnt, al1, ar1, xlb, b1, hb);

    // ---- layer 2 ----
    gemm2_mfma_kernel<<<(N_NODES + 63) / 64, 256, 0, stream>>>(hb, W2b, xl2b);
    alphas_kernel<OUT_C><<<NB4, 256, 0, stream>>>(xl2b, atl2, atr2, al2, ar2);
    agg_kernel<OUT_C, 1, 5><<<NB8, 256, 0, stream>>>(
        csr_src, row_start, cnt, al2, ar2, xl2b, b2, out);
}